// Round 1
// baseline (8568.159 us; speedup 1.0000x reference)
//
#include <hip/hip_runtime.h>
#include <cstdint>
#include <cstddef>

#define HDIM 256
#define DIN 128
#define EPSV 1e-5f

// ---------------- degree / normalization ----------------
__global__ __launch_bounds__(256) void deg_init_k(float* deg, int n) {
  int i = blockIdx.x * 256 + threadIdx.x;
  if (i < n) deg[i] = 1.0f;  // self-loop contributes 1
}

__global__ __launch_bounds__(256) void deg_scatter_k(const int* __restrict__ col,
                                                     float* deg, int e) {
  int i = blockIdx.x * 256 + threadIdx.x;
  if (i < e) atomicAdd(&deg[col[i]], 1.0f);
}

__global__ __launch_bounds__(256) void deg_fin_k(float* deg, int n) {
  int i = blockIdx.x * 256 + threadIdx.x;
  if (i < n) deg[i] = rsqrtf(deg[i]);  // deg >= 1 always (self-loop)
}

// ---------------- GEMM: out[n,C] = A[n,K] @ W[K,C], fused epilogue ----------------
// MODE 0: out[r][c] = acc * sb[r]            (row scale by dis -> xws)
// MODE 1: out[r][c] = relu(acc + sb[c])      (bias + relu -> MLP hidden h)
template<int MODE>
__global__ __launch_bounds__(256) void gemm_k(
    const float* __restrict__ A, const float* __restrict__ W,
    float* __restrict__ out, const float* __restrict__ sb,
    int n, int K, int C) {
  __shared__ float As[32][68];  // transposed A tile [k][m], pad 68 keeps 16B align
  __shared__ float Bs[32][64];
  const int t = threadIdx.x;
  const int tn = t & 15, tm = t >> 4;
  const int m0 = blockIdx.x * 64, n0 = blockIdx.y * 64;
  float acc[4][4];
#pragma unroll
  for (int i = 0; i < 4; ++i)
#pragma unroll
    for (int j = 0; j < 4; ++j) acc[i][j] = 0.f;

  for (int k0 = 0; k0 < K; k0 += 32) {
#pragma unroll
    for (int it = 0; it < 2; ++it) {
      int idx = t + it * 256;
      // A tile: 64 rows x 32 k, float4 along k, store transposed
      int k4 = idx & 7, m = idx >> 3;
      float4 v = make_float4(0.f, 0.f, 0.f, 0.f);
      if (m0 + m < n) v = *(const float4*)(A + (size_t)(m0 + m) * K + k0 + k4 * 4);
      As[k4 * 4 + 0][m] = v.x;
      As[k4 * 4 + 1][m] = v.y;
      As[k4 * 4 + 2][m] = v.z;
      As[k4 * 4 + 3][m] = v.w;
      // B tile: 32 k x 64 n, natural layout
      int n4 = idx & 15, kk = idx >> 4;
      *(float4*)&Bs[kk][n4 * 4] = *(const float4*)(W + (size_t)(k0 + kk) * C + n0 + n4 * 4);
    }
    __syncthreads();
#pragma unroll
    for (int k = 0; k < 32; ++k) {
      float4 a4 = *(const float4*)&As[k][tm * 4];
      float4 b4 = *(const float4*)&Bs[k][tn * 4];
      float a[4] = {a4.x, a4.y, a4.z, a4.w};
      float b[4] = {b4.x, b4.y, b4.z, b4.w};
#pragma unroll
      for (int i = 0; i < 4; ++i)
#pragma unroll
        for (int j = 0; j < 4; ++j) acc[i][j] += a[i] * b[j];
    }
    __syncthreads();
  }

  if (MODE == 0) {
#pragma unroll
    for (int i = 0; i < 4; ++i) {
      int r = m0 + tm * 4 + i;
      if (r < n) {
        float s = sb[r];
        float4 v = make_float4(acc[i][0] * s, acc[i][1] * s, acc[i][2] * s, acc[i][3] * s);
        *(float4*)(out + (size_t)r * C + n0 + tn * 4) = v;
      }
    }
  } else {
    float4 bb = *(const float4*)(sb + n0 + tn * 4);
#pragma unroll
    for (int i = 0; i < 4; ++i) {
      int r = m0 + tm * 4 + i;
      if (r < n) {
        float4 v;
        v.x = fmaxf(acc[i][0] + bb.x, 0.f);
        v.y = fmaxf(acc[i][1] + bb.y, 0.f);
        v.z = fmaxf(acc[i][2] + bb.z, 0.f);
        v.w = fmaxf(acc[i][3] + bb.w, 0.f);
        *(float4*)(out + (size_t)r * C + n0 + tn * 4) = v;
      }
    }
  }
}

// ---------------- edge scatter: agg[col] += xws[row] ----------------
// one wave (64 lanes) per edge; lane handles 4 contiguous floats
__global__ __launch_bounds__(256) void scatter_k(
    const int* __restrict__ row, const int* __restrict__ col,
    const float* __restrict__ xws, float* __restrict__ agg, int e) {
  int w = (blockIdx.x * 256 + threadIdx.x) >> 6;
  int lane = threadIdx.x & 63;
  if (w >= e) return;
  int r = row[w], c = col[w];
  float4 v = *(const float4*)(xws + (size_t)r * HDIM + lane * 4);
  float* dst = agg + (size_t)c * HDIM + lane * 4;
  atomicAdd(dst + 0, v.x);
  atomicAdd(dst + 1, v.y);
  atomicAdd(dst + 2, v.z);
  atomicAdd(dst + 3, v.w);
}

// ---------------- fused bias + LayerNorm + ReLU + residual ----------------
// val = dis[i]*(agg[i]+xws[i]) + bias   (self-loop folded: xws[i]*dis[i]^2)
// MODE 0: out = relu(ln(val))
// MODE 1: out = relu(ln(val)) + 0.7*xprev
// MODE 2: out = relu(ln(val))*0.7 + xprev
template<int MODE>
__global__ __launch_bounds__(256) void ln_k(
    const float* __restrict__ agg, const float* __restrict__ xws,
    const float* __restrict__ dis, const float* __restrict__ bias,
    const float* __restrict__ g, const float* __restrict__ be,
    const float* __restrict__ xprev, float* __restrict__ out, int n) {
  int i = blockIdx.x * 4 + (threadIdx.x >> 6);
  int lane = threadIdx.x & 63;
  if (i >= n) return;
  float di = dis[i];
  float4 v = *(const float4*)(agg + (size_t)i * HDIM + lane * 4);
  float4 xw = *(const float4*)(xws + (size_t)i * HDIM + lane * 4);
  float4 b4 = *(const float4*)(bias + lane * 4);
  v.x = (v.x + xw.x) * di + b4.x;
  v.y = (v.y + xw.y) * di + b4.y;
  v.z = (v.z + xw.z) * di + b4.z;
  v.w = (v.w + xw.w) * di + b4.w;
  float s = v.x + v.y + v.z + v.w;
  float s2 = v.x * v.x + v.y * v.y + v.z * v.z + v.w * v.w;
#pragma unroll
  for (int off = 1; off < 64; off <<= 1) {
    s += __shfl_xor(s, off);
    s2 += __shfl_xor(s2, off);
  }
  float mu = s * (1.f / HDIM);
  float inv = rsqrtf(s2 * (1.f / HDIM) - mu * mu + EPSV);
  float4 g4 = *(const float4*)(g + lane * 4);
  float4 e4 = *(const float4*)(be + lane * 4);
  float4 o;
  o.x = fmaxf((v.x - mu) * inv * g4.x + e4.x, 0.f);
  o.y = fmaxf((v.y - mu) * inv * g4.y + e4.y, 0.f);
  o.z = fmaxf((v.z - mu) * inv * g4.z + e4.z, 0.f);
  o.w = fmaxf((v.w - mu) * inv * g4.w + e4.w, 0.f);
  if (MODE == 1) {
    float4 p = *(const float4*)(xprev + (size_t)i * HDIM + lane * 4);
    o.x += 0.7f * p.x; o.y += 0.7f * p.y; o.z += 0.7f * p.z; o.w += 0.7f * p.w;
  } else if (MODE == 2) {
    float4 p = *(const float4*)(xprev + (size_t)i * HDIM + lane * 4);
    o.x = o.x * 0.7f + p.x; o.y = o.y * 0.7f + p.y;
    o.z = o.z * 0.7f + p.z; o.w = o.w * 0.7f + p.w;
  }
  *(float4*)(out + (size_t)i * HDIM + lane * 4) = o;
}

// ---------------- final dot: out[i] = h[i,:] @ Wf2 + bf2 ----------------
__global__ __launch_bounds__(256) void dot_k(
    const float* __restrict__ h, const float* __restrict__ w,
    const float* __restrict__ bf2, float* __restrict__ out, int n) {
  int i = blockIdx.x * 4 + (threadIdx.x >> 6);
  int lane = threadIdx.x & 63;
  if (i >= n) return;
  float2 hv = *(const float2*)(h + (size_t)i * 128 + lane * 2);
  float2 wv = *(const float2*)(w + lane * 2);
  float p = hv.x * wv.x + hv.y * wv.y;
#pragma unroll
  for (int off = 1; off < 64; off <<= 1) p += __shfl_xor(p, off);
  if (lane == 0) out[i] = p + bf2[0];
}

extern "C" void kernel_launch(void* const* d_in, const int* in_sizes, int n_in,
                              void* d_out, int out_size, void* d_ws, size_t ws_size,
                              hipStream_t stream) {
  const float* x   = (const float*)d_in[0];
  const int*   ei  = (const int*)d_in[1];
  const float* W1  = (const float*)d_in[2];
  const float* b1  = (const float*)d_in[3];
  const float* g1  = (const float*)d_in[4];
  const float* be1 = (const float*)d_in[5];
  const float* W2  = (const float*)d_in[6];
  const float* b2  = (const float*)d_in[7];
  const float* g2  = (const float*)d_in[8];
  const float* be2 = (const float*)d_in[9];
  const float* W3  = (const float*)d_in[10];
  const float* b3  = (const float*)d_in[11];
  const float* g3  = (const float*)d_in[12];
  const float* be3 = (const float*)d_in[13];
  const float* Wf1 = (const float*)d_in[14];
  const float* bf1 = (const float*)d_in[15];
  const float* Wf2 = (const float*)d_in[16];
  const float* bf2 = (const float*)d_in[17];
  float* out = (float*)d_out;

  const int n = in_sizes[0] / DIN;   // 50000
  const int e = in_sizes[1] / 2;     // 800000
  const int* row = ei;               // edge_index[0] = sources
  const int* col = ei + e;           // edge_index[1] = targets

  char* ws = (char*)d_ws;
  size_t off = 0;
  auto alloc = [&](size_t bytes) -> void* {
    void* p = ws + off;
    off = (off + bytes + 255) & ~(size_t)255;
    return p;
  };
  float* dis = (float*)alloc((size_t)n * 4);
  float* xws = (float*)alloc((size_t)n * HDIM * 4);
  float* agg = (float*)alloc((size_t)n * HDIM * 4);
  float* x1  = (float*)alloc((size_t)n * HDIM * 4);
  float* x2  = (float*)alloc((size_t)n * HDIM * 4);
  float* x3  = x1;   // x1 dead once x2 computed
  float* h   = xws;  // xws dead after LN3

  const int nb  = (n + 255) / 256;
  const int sbk = (e + 3) / 4;       // one wave per edge, 4 waves per block
  const int lnb = (n + 3) / 4;
  dim3 gg((n + 63) / 64, HDIM / 64);
  dim3 gg2((n + 63) / 64, 128 / 64);

  // normalization coefficients
  deg_init_k<<<nb, 256, 0, stream>>>(dis, n);
  deg_scatter_k<<<(e + 255) / 256, 256, 0, stream>>>(col, dis, e);
  deg_fin_k<<<nb, 256, 0, stream>>>(dis, n);

  // layer 1
  gemm_k<0><<<gg, 256, 0, stream>>>(x, W1, xws, dis, n, DIN, HDIM);
  hipMemsetAsync(agg, 0, (size_t)n * HDIM * 4, stream);
  scatter_k<<<sbk, 256, 0, stream>>>(row, col, xws, agg, e);
  ln_k<0><<<lnb, 256, 0, stream>>>(agg, xws, dis, b1, g1, be1, nullptr, x1, n);

  // layer 2
  gemm_k<0><<<gg, 256, 0, stream>>>(x1, W2, xws, dis, n, HDIM, HDIM);
  hipMemsetAsync(agg, 0, (size_t)n * HDIM * 4, stream);
  scatter_k<<<sbk, 256, 0, stream>>>(row, col, xws, agg, e);
  ln_k<1><<<lnb, 256, 0, stream>>>(agg, xws, dis, b2, g2, be2, x1, x2, n);

  // layer 3
  gemm_k<0><<<gg, 256, 0, stream>>>(x2, W3, xws, dis, n, HDIM, HDIM);
  hipMemsetAsync(agg, 0, (size_t)n * HDIM * 4, stream);
  scatter_k<<<sbk, 256, 0, stream>>>(row, col, xws, agg, e);
  ln_k<2><<<lnb, 256, 0, stream>>>(agg, xws, dis, b3, g3, be3, x2, x3, n);

  // MLP head
  gemm_k<1><<<gg2, 256, 0, stream>>>(x3, Wf1, h, bf1, n, HDIM, 128);
  dot_k<<<lnb, 256, 0, stream>>>(h, Wf2, bf2, out, n);
}

// Round 2
// 924.144 us; speedup vs baseline: 9.2715x; 9.2715x over previous
//
#include <hip/hip_runtime.h>
#include <cstdint>
#include <cstddef>

#define HDIM 256
#define DIN 128
#define EPSV 1e-5f

// ---------------- CSR build ----------------
__global__ __launch_bounds__(256) void zero_i_k(int* deg, int* cur, int n) {
  int i = blockIdx.x * 256 + threadIdx.x;
  if (i < n) { deg[i] = 0; cur[i] = 0; }
}

__global__ __launch_bounds__(256) void hist_k(const int* __restrict__ col,
                                              int* deg, int e) {
  int i = blockIdx.x * 256 + threadIdx.x;
  if (i < e) atomicAdd(&deg[col[i]], 1);
}

__global__ __launch_bounds__(256) void fin_k(const int* __restrict__ deg,
                                             float* dis, int n) {
  int i = blockIdx.x * 256 + threadIdx.x;
  if (i < n) dis[i] = rsqrtf((float)(deg[i] + 1));  // +1 self-loop
}

// single-block exclusive scan over n counts -> row_ptr[0..n]
__global__ __launch_bounds__(1024) void scan_k(const int* __restrict__ deg,
                                               int* row_ptr, int n) {
  __shared__ int tmp[1024];
  const int tid = threadIdx.x;
  int carry = 0;  // uniform across threads
  for (int base = 0; base < n; base += 1024) {
    int v = (base + tid < n) ? deg[base + tid] : 0;
    tmp[tid] = v;
    __syncthreads();
#pragma unroll
    for (int off = 1; off < 1024; off <<= 1) {
      int t = (tid >= off) ? tmp[tid - off] : 0;
      __syncthreads();
      tmp[tid] += t;
      __syncthreads();
    }
    if (base + tid < n) row_ptr[base + tid] = carry + tmp[tid] - v;
    int total = tmp[1023];
    __syncthreads();
    carry += total;
  }
  if (tid == 0) row_ptr[n] = carry;
}

__global__ __launch_bounds__(256) void fill_k(const int* __restrict__ row,
                                              const int* __restrict__ col,
                                              const int* __restrict__ row_ptr,
                                              int* cur, int* srcs, int e) {
  int i = blockIdx.x * 256 + threadIdx.x;
  if (i < e) {
    int c = col[i];
    int p = row_ptr[c] + atomicAdd(&cur[c], 1);
    srcs[p] = row[i];
  }
}

// ---------------- GEMM: out[n,C] = A[n,K] @ W[K,C], fused epilogue ----------------
// MODE 0: out[r][c] = acc * sb[r]            (row scale by dis -> xws)
// MODE 1: out[r][c] = relu(acc + sb[c])      (bias + relu -> MLP hidden h)
template<int MODE>
__global__ __launch_bounds__(256) void gemm_k(
    const float* __restrict__ A, const float* __restrict__ W,
    float* __restrict__ out, const float* __restrict__ sb,
    int n, int K, int C) {
  __shared__ float As[32][68];  // transposed A tile [k][m]
  __shared__ float Bs[32][64];
  const int t = threadIdx.x;
  const int tn = t & 15, tm = t >> 4;
  const int m0 = blockIdx.x * 64, n0 = blockIdx.y * 64;
  float acc[4][4];
#pragma unroll
  for (int i = 0; i < 4; ++i)
#pragma unroll
    for (int j = 0; j < 4; ++j) acc[i][j] = 0.f;

  for (int k0 = 0; k0 < K; k0 += 32) {
#pragma unroll
    for (int it = 0; it < 2; ++it) {
      int idx = t + it * 256;
      int k4 = idx & 7, m = idx >> 3;
      float4 v = make_float4(0.f, 0.f, 0.f, 0.f);
      if (m0 + m < n) v = *(const float4*)(A + (size_t)(m0 + m) * K + k0 + k4 * 4);
      As[k4 * 4 + 0][m] = v.x;
      As[k4 * 4 + 1][m] = v.y;
      As[k4 * 4 + 2][m] = v.z;
      As[k4 * 4 + 3][m] = v.w;
      int n4 = idx & 15, kk = idx >> 4;
      *(float4*)&Bs[kk][n4 * 4] = *(const float4*)(W + (size_t)(k0 + kk) * C + n0 + n4 * 4);
    }
    __syncthreads();
#pragma unroll
    for (int k = 0; k < 32; ++k) {
      float4 a4 = *(const float4*)&As[k][tm * 4];
      float4 b4 = *(const float4*)&Bs[k][tn * 4];
      float a[4] = {a4.x, a4.y, a4.z, a4.w};
      float b[4] = {b4.x, b4.y, b4.z, b4.w};
#pragma unroll
      for (int i = 0; i < 4; ++i)
#pragma unroll
        for (int j = 0; j < 4; ++j) acc[i][j] += a[i] * b[j];
    }
    __syncthreads();
  }

  if (MODE == 0) {
#pragma unroll
    for (int i = 0; i < 4; ++i) {
      int r = m0 + tm * 4 + i;
      if (r < n) {
        float s = sb[r];
        float4 v = make_float4(acc[i][0] * s, acc[i][1] * s, acc[i][2] * s, acc[i][3] * s);
        *(float4*)(out + (size_t)r * C + n0 + tn * 4) = v;
      }
    }
  } else {
    float4 bb = *(const float4*)(sb + n0 + tn * 4);
#pragma unroll
    for (int i = 0; i < 4; ++i) {
      int r = m0 + tm * 4 + i;
      if (r < n) {
        float4 v;
        v.x = fmaxf(acc[i][0] + bb.x, 0.f);
        v.y = fmaxf(acc[i][1] + bb.y, 0.f);
        v.z = fmaxf(acc[i][2] + bb.z, 0.f);
        v.w = fmaxf(acc[i][3] + bb.w, 0.f);
        *(float4*)(out + (size_t)r * C + n0 + tn * 4) = v;
      }
    }
  }
}

// ---------------- fused gather + bias + LayerNorm + ReLU + residual ----------------
// acc = sum_{in-edges} xws[src] + xws[i]; val = acc*dis[i] + bias; LN; relu; residual
// MODE 0: out = relu(ln(val))
// MODE 1: out = relu(ln(val)) + 0.7*xprev
// MODE 2: out = relu(ln(val))*0.7 + xprev
template<int MODE>
__global__ __launch_bounds__(256) void gather_ln_k(
    const float* __restrict__ xws, const int* __restrict__ row_ptr,
    const int* __restrict__ srcs, const float* __restrict__ dis,
    const float* __restrict__ bias, const float* __restrict__ g,
    const float* __restrict__ be, const float* __restrict__ xprev,
    float* __restrict__ out, int n) {
  int i = blockIdx.x * 4 + (threadIdx.x >> 6);
  int lane = threadIdx.x & 63;
  if (i >= n) return;
  int beg = row_ptr[i], end = row_ptr[i + 1];
  float4 acc = *(const float4*)(xws + (size_t)i * HDIM + lane * 4);  // self-loop
  int j = beg;
  for (; j + 4 <= end; j += 4) {
    int r0 = srcs[j], r1 = srcs[j + 1], r2 = srcs[j + 2], r3 = srcs[j + 3];
    float4 v0 = *(const float4*)(xws + (size_t)r0 * HDIM + lane * 4);
    float4 v1 = *(const float4*)(xws + (size_t)r1 * HDIM + lane * 4);
    float4 v2 = *(const float4*)(xws + (size_t)r2 * HDIM + lane * 4);
    float4 v3 = *(const float4*)(xws + (size_t)r3 * HDIM + lane * 4);
    acc.x += (v0.x + v1.x) + (v2.x + v3.x);
    acc.y += (v0.y + v1.y) + (v2.y + v3.y);
    acc.z += (v0.z + v1.z) + (v2.z + v3.z);
    acc.w += (v0.w + v1.w) + (v2.w + v3.w);
  }
  for (; j < end; ++j) {
    int r = srcs[j];
    float4 v = *(const float4*)(xws + (size_t)r * HDIM + lane * 4);
    acc.x += v.x; acc.y += v.y; acc.z += v.z; acc.w += v.w;
  }
  float di = dis[i];
  float4 b4 = *(const float4*)(bias + lane * 4);
  float4 v;
  v.x = acc.x * di + b4.x;
  v.y = acc.y * di + b4.y;
  v.z = acc.z * di + b4.z;
  v.w = acc.w * di + b4.w;
  float s = v.x + v.y + v.z + v.w;
  float s2 = v.x * v.x + v.y * v.y + v.z * v.z + v.w * v.w;
#pragma unroll
  for (int off = 1; off < 64; off <<= 1) {
    s += __shfl_xor(s, off);
    s2 += __shfl_xor(s2, off);
  }
  float mu = s * (1.f / HDIM);
  float inv = rsqrtf(s2 * (1.f / HDIM) - mu * mu + EPSV);
  float4 g4 = *(const float4*)(g + lane * 4);
  float4 e4 = *(const float4*)(be + lane * 4);
  float4 o;
  o.x = fmaxf((v.x - mu) * inv * g4.x + e4.x, 0.f);
  o.y = fmaxf((v.y - mu) * inv * g4.y + e4.y, 0.f);
  o.z = fmaxf((v.z - mu) * inv * g4.z + e4.z, 0.f);
  o.w = fmaxf((v.w - mu) * inv * g4.w + e4.w, 0.f);
  if (MODE == 1) {
    float4 p = *(const float4*)(xprev + (size_t)i * HDIM + lane * 4);
    o.x += 0.7f * p.x; o.y += 0.7f * p.y; o.z += 0.7f * p.z; o.w += 0.7f * p.w;
  } else if (MODE == 2) {
    float4 p = *(const float4*)(xprev + (size_t)i * HDIM + lane * 4);
    o.x = o.x * 0.7f + p.x; o.y = o.y * 0.7f + p.y;
    o.z = o.z * 0.7f + p.z; o.w = o.w * 0.7f + p.w;
  }
  *(float4*)(out + (size_t)i * HDIM + lane * 4) = o;
}

// ---------------- final dot: out[i] = h[i,:] @ Wf2 + bf2 ----------------
__global__ __launch_bounds__(256) void dot_k(
    const float* __restrict__ h, const float* __restrict__ w,
    const float* __restrict__ bf2, float* __restrict__ out, int n) {
  int i = blockIdx.x * 4 + (threadIdx.x >> 6);
  int lane = threadIdx.x & 63;
  if (i >= n) return;
  float2 hv = *(const float2*)(h + (size_t)i * 128 + lane * 2);
  float2 wv = *(const float2*)(w + lane * 2);
  float p = hv.x * wv.x + hv.y * wv.y;
#pragma unroll
  for (int off = 1; off < 64; off <<= 1) p += __shfl_xor(p, off);
  if (lane == 0) out[i] = p + bf2[0];
}

extern "C" void kernel_launch(void* const* d_in, const int* in_sizes, int n_in,
                              void* d_out, int out_size, void* d_ws, size_t ws_size,
                              hipStream_t stream) {
  const float* x   = (const float*)d_in[0];
  const int*   ei  = (const int*)d_in[1];
  const float* W1  = (const float*)d_in[2];
  const float* b1  = (const float*)d_in[3];
  const float* g1  = (const float*)d_in[4];
  const float* be1 = (const float*)d_in[5];
  const float* W2  = (const float*)d_in[6];
  const float* b2  = (const float*)d_in[7];
  const float* g2  = (const float*)d_in[8];
  const float* be2 = (const float*)d_in[9];
  const float* W3  = (const float*)d_in[10];
  const float* b3  = (const float*)d_in[11];
  const float* g3  = (const float*)d_in[12];
  const float* be3 = (const float*)d_in[13];
  const float* Wf1 = (const float*)d_in[14];
  const float* bf1 = (const float*)d_in[15];
  const float* Wf2 = (const float*)d_in[16];
  const float* bf2 = (const float*)d_in[17];
  float* out = (float*)d_out;

  const int n = in_sizes[0] / DIN;   // 50000
  const int e = in_sizes[1] / 2;     // 800000
  const int* row = ei;               // edge_index[0] = sources
  const int* col = ei + e;           // edge_index[1] = targets

  char* ws = (char*)d_ws;
  size_t off = 0;
  auto alloc = [&](size_t bytes) -> void* {
    void* p = ws + off;
    off = (off + bytes + 255) & ~(size_t)255;
    return p;
  };
  float* dis     = (float*)alloc((size_t)n * 4);
  int*   deg_i   = (int*)alloc((size_t)n * 4);
  int*   cur     = (int*)alloc((size_t)n * 4);
  int*   row_ptr = (int*)alloc((size_t)(n + 1) * 4);
  int*   srcs    = (int*)alloc((size_t)e * 4);
  float* xws     = (float*)alloc((size_t)n * HDIM * 4);
  float* x1      = (float*)alloc((size_t)n * HDIM * 4);
  float* x2      = (float*)alloc((size_t)n * HDIM * 4);
  float* x3      = x1;   // x1 dead once x2 computed
  float* h       = x2;   // x2 dead after layer-3 gather

  const int nb  = (n + 255) / 256;
  const int eb  = (e + 255) / 256;
  const int lnb = (n + 3) / 4;
  dim3 gg((n + 63) / 64, HDIM / 64);
  dim3 gg2((n + 63) / 64, 128 / 64);

  // CSR build + normalization
  zero_i_k<<<nb, 256, 0, stream>>>(deg_i, cur, n);
  hist_k<<<eb, 256, 0, stream>>>(col, deg_i, e);
  fin_k<<<nb, 256, 0, stream>>>(deg_i, dis, n);
  scan_k<<<1, 1024, 0, stream>>>(deg_i, row_ptr, n);
  fill_k<<<eb, 256, 0, stream>>>(row, col, row_ptr, cur, srcs, e);

  // layer 1
  gemm_k<0><<<gg, 256, 0, stream>>>(x, W1, xws, dis, n, DIN, HDIM);
  gather_ln_k<0><<<lnb, 256, 0, stream>>>(xws, row_ptr, srcs, dis, b1, g1, be1, nullptr, x1, n);

  // layer 2
  gemm_k<0><<<gg, 256, 0, stream>>>(x1, W2, xws, dis, n, HDIM, HDIM);
  gather_ln_k<1><<<lnb, 256, 0, stream>>>(xws, row_ptr, srcs, dis, b2, g2, be2, x1, x2, n);

  // layer 3
  gemm_k<0><<<gg, 256, 0, stream>>>(x2, W3, xws, dis, n, HDIM, HDIM);
  gather_ln_k<2><<<lnb, 256, 0, stream>>>(xws, row_ptr, srcs, dis, b3, g3, be3, x2, x3, n);

  // MLP head (h overwrites x2 after its last read in layer-3 gather)
  gemm_k<1><<<gg2, 256, 0, stream>>>(x3, Wf1, h, bf1, n, HDIM, 128);
  dot_k<<<lnb, 256, 0, stream>>>(h, Wf2, bf2, out, n);
}

// Round 3
// 671.637 us; speedup vs baseline: 12.7571x; 1.3760x over previous
//
#include <hip/hip_runtime.h>
#include <cstdint>
#include <cstddef>

#define HDIM 256
#define DIN 128
#define EPSV 1e-5f

typedef __attribute__((ext_vector_type(8))) short short8;   // 8 bf16 = 4 VGPRs
typedef __attribute__((ext_vector_type(4))) float f32x4;    // MFMA acc

__device__ __forceinline__ float bf2f(unsigned int u16) {
  union { unsigned int i; float f; } v; v.i = u16 << 16; return v.f;
}
__device__ __forceinline__ unsigned short f2bf(float f) {
  union { float f; unsigned int i; } v; v.f = f;
  unsigned int u = v.i;
  return (unsigned short)((u + 0x7fffu + ((u >> 16) & 1u)) >> 16);
}
// load 4 bf16 (8B) -> float4
__device__ __forceinline__ float4 ldbf4(const unsigned short* p) {
  uint2 v = *(const uint2*)p;
  return make_float4(bf2f(v.x & 0xffffu), bf2f(v.x >> 16),
                     bf2f(v.y & 0xffffu), bf2f(v.y >> 16));
}
__device__ __forceinline__ void stbf4(unsigned short* p, float a, float b, float c, float d) {
  uint2 o;
  o.x = (unsigned int)f2bf(a) | ((unsigned int)f2bf(b) << 16);
  o.y = (unsigned int)f2bf(c) | ((unsigned int)f2bf(d) << 16);
  *(uint2*)p = o;
}

// ---------------- CSR build ----------------
__global__ __launch_bounds__(256) void zero_i_k(int* deg, int* cur, int n) {
  int i = blockIdx.x * 256 + threadIdx.x;
  if (i < n) { deg[i] = 0; cur[i] = 0; }
}

__global__ __launch_bounds__(256) void hist_k(const int* __restrict__ col, int* deg, int e) {
  int i = blockIdx.x * 256 + threadIdx.x;
  if (i < e) atomicAdd(&deg[col[i]], 1);
}

__global__ __launch_bounds__(256) void fin_k(const int* __restrict__ deg, float* dis, int n) {
  int i = blockIdx.x * 256 + threadIdx.x;
  if (i < n) dis[i] = rsqrtf((float)(deg[i] + 1));  // +1 self-loop
}

__global__ __launch_bounds__(1024) void scan_k(const int* __restrict__ deg,
                                               int* row_ptr, int n) {
  __shared__ int tmp[1024];
  const int tid = threadIdx.x;
  int carry = 0;
  for (int base = 0; base < n; base += 1024) {
    int v = (base + tid < n) ? deg[base + tid] : 0;
    tmp[tid] = v;
    __syncthreads();
#pragma unroll
    for (int off = 1; off < 1024; off <<= 1) {
      int t = (tid >= off) ? tmp[tid - off] : 0;
      __syncthreads();
      tmp[tid] += t;
      __syncthreads();
    }
    if (base + tid < n) row_ptr[base + tid] = carry + tmp[tid] - v;
    int total = tmp[1023];
    __syncthreads();
    carry += total;
  }
  if (tid == 0) row_ptr[n] = carry;
}

__global__ __launch_bounds__(256) void fill_k(const int* __restrict__ row,
                                              const int* __restrict__ col,
                                              const int* __restrict__ row_ptr,
                                              int* cur, int* srcs, int e) {
  int i = blockIdx.x * 256 + threadIdx.x;
  if (i < e) {
    int c = col[i];
    int p = row_ptr[c] + atomicAdd(&cur[c], 1);
    srcs[p] = row[i];
  }
}

// ---------------- weight pack: W[K,C] fp32 -> bf16 MFMA A-operand fragments ----
// layout: [kb][ns][lane][j] ; value = W[kb*32 + (lane>>4)*8 + j][ns*16 + (lane&15)]
__global__ __launch_bounds__(256) void pack_k(const float* __restrict__ W,
                                              unsigned short* __restrict__ out,
                                              int K, int C) {
  int idx = blockIdx.x * 256 + threadIdx.x;
  if (idx >= K * C) return;
  int j = idx & 7, lane = (idx >> 3) & 63, rest = idx >> 9;
  int NSUB = C >> 4;
  int ns = rest % NSUB, kb = rest / NSUB;
  int k = kb * 32 + (lane >> 4) * 8 + j;
  int c = ns * 16 + (lane & 15);
  out[idx] = f2bf(W[(size_t)k * C + c]);
}

// ---------------- fp32 -> bf16 cast ----------------
__global__ __launch_bounds__(256) void cvt_k(const float* __restrict__ in,
                                             unsigned short* __restrict__ out, int tot) {
  int i = blockIdx.x * 256 + threadIdx.x;
  if (i < tot) out[i] = f2bf(in[i]);
}

// ---------------- bf16 MFMA GEMM: out[n,CN] = A[n,K] @ W[K,CN] ----------------
// swapped-operand trick: mfma(w_frag, a_frag) -> lane holds 4 consecutive cols of
// row (m0 + lane&15); cols = ns*16 + (lane>>4)*4 + r.
// MODE 0: out = acc * sb[row]  (dis scale)   MODE 1: out = relu(acc + sb[col])
template<int MODE, int K, int CN>
__global__ __launch_bounds__(256) void gemm_k(
    const unsigned short* __restrict__ A, const unsigned short* __restrict__ Wp,
    unsigned short* __restrict__ out, const float* __restrict__ sb, int n) {
  constexpr int NSUB = CN / 16;
  const int t = threadIdx.x;
  const int w = t >> 6, lane = t & 63;
  const int g = lane >> 4, i = lane & 15;
  const int mrow = blockIdx.x * 64 + w * 16 + i;
  const int mload = mrow < n ? mrow : n - 1;

  f32x4 acc[NSUB];
#pragma unroll
  for (int ns = 0; ns < NSUB; ++ns) acc[ns] = (f32x4){0.f, 0.f, 0.f, 0.f};

  const unsigned short* arow = A + (size_t)mload * K + g * 8;
#pragma unroll 2
  for (int kc = 0; kc < K / 32; ++kc) {
    short8 af = *(const short8*)(arow + kc * 32);
    const short8* wp = (const short8*)(Wp) + (size_t)(kc * NSUB) * 64 + lane;
#pragma unroll
    for (int ns = 0; ns < NSUB; ++ns) {
      short8 wf = wp[ns * 64];
      acc[ns] = __builtin_amdgcn_mfma_f32_16x16x32_bf16(wf, af, acc[ns], 0, 0, 0);
    }
  }

  if (mrow < n) {
    unsigned short* op = out + (size_t)mrow * CN + g * 4;
    if (MODE == 0) {
      float s = sb[mrow];
#pragma unroll
      for (int ns = 0; ns < NSUB; ++ns)
        stbf4(op + ns * 16, acc[ns][0] * s, acc[ns][1] * s, acc[ns][2] * s, acc[ns][3] * s);
    } else {
#pragma unroll
      for (int ns = 0; ns < NSUB; ++ns) {
        float4 b4 = *(const float4*)(sb + ns * 16 + g * 4);
        stbf4(op + ns * 16,
              fmaxf(acc[ns][0] + b4.x, 0.f), fmaxf(acc[ns][1] + b4.y, 0.f),
              fmaxf(acc[ns][2] + b4.z, 0.f), fmaxf(acc[ns][3] + b4.w, 0.f));
      }
    }
  }
}

// ---------------- fused gather + bias + LayerNorm + ReLU + residual (bf16 io) ----
// MODE 0: out = relu(ln(val))
// MODE 1: out = relu(ln(val)) + 0.7*xprev
// MODE 2: out = relu(ln(val))*0.7 + xprev
template<int MODE>
__global__ __launch_bounds__(256) void gather_ln_k(
    const unsigned short* __restrict__ xws, const int* __restrict__ row_ptr,
    const int* __restrict__ srcs, const float* __restrict__ dis,
    const float* __restrict__ bias, const float* __restrict__ g,
    const float* __restrict__ be, const unsigned short* __restrict__ xprev,
    unsigned short* __restrict__ out, int n) {
  int i = blockIdx.x * 4 + (threadIdx.x >> 6);
  int lane = threadIdx.x & 63;
  if (i >= n) return;
  int beg = row_ptr[i], end = row_ptr[i + 1];
  const int co = lane * 4;
  float4 acc = ldbf4(xws + (size_t)i * HDIM + co);  // self-loop
  int j = beg;
  for (; j + 4 <= end; j += 4) {
    int r0 = srcs[j], r1 = srcs[j + 1], r2 = srcs[j + 2], r3 = srcs[j + 3];
    float4 v0 = ldbf4(xws + (size_t)r0 * HDIM + co);
    float4 v1 = ldbf4(xws + (size_t)r1 * HDIM + co);
    float4 v2 = ldbf4(xws + (size_t)r2 * HDIM + co);
    float4 v3 = ldbf4(xws + (size_t)r3 * HDIM + co);
    acc.x += (v0.x + v1.x) + (v2.x + v3.x);
    acc.y += (v0.y + v1.y) + (v2.y + v3.y);
    acc.z += (v0.z + v1.z) + (v2.z + v3.z);
    acc.w += (v0.w + v1.w) + (v2.w + v3.w);
  }
  for (; j < end; ++j) {
    float4 v = ldbf4(xws + (size_t)srcs[j] * HDIM + co);
    acc.x += v.x; acc.y += v.y; acc.z += v.z; acc.w += v.w;
  }
  float di = dis[i];
  float4 b4 = *(const float4*)(bias + co);
  float4 v;
  v.x = acc.x * di + b4.x;
  v.y = acc.y * di + b4.y;
  v.z = acc.z * di + b4.z;
  v.w = acc.w * di + b4.w;
  float s = v.x + v.y + v.z + v.w;
  float s2 = v.x * v.x + v.y * v.y + v.z * v.z + v.w * v.w;
#pragma unroll
  for (int off = 1; off < 64; off <<= 1) {
    s += __shfl_xor(s, off);
    s2 += __shfl_xor(s2, off);
  }
  float mu = s * (1.f / HDIM);
  float inv = rsqrtf(s2 * (1.f / HDIM) - mu * mu + EPSV);
  float4 g4 = *(const float4*)(g + co);
  float4 e4 = *(const float4*)(be + co);
  float4 o;
  o.x = fmaxf((v.x - mu) * inv * g4.x + e4.x, 0.f);
  o.y = fmaxf((v.y - mu) * inv * g4.y + e4.y, 0.f);
  o.z = fmaxf((v.z - mu) * inv * g4.z + e4.z, 0.f);
  o.w = fmaxf((v.w - mu) * inv * g4.w + e4.w, 0.f);
  if (MODE == 1) {
    float4 p = ldbf4(xprev + (size_t)i * HDIM + co);
    o.x += 0.7f * p.x; o.y += 0.7f * p.y; o.z += 0.7f * p.z; o.w += 0.7f * p.w;
  } else if (MODE == 2) {
    float4 p = ldbf4(xprev + (size_t)i * HDIM + co);
    o.x = o.x * 0.7f + p.x; o.y = o.y * 0.7f + p.y;
    o.z = o.z * 0.7f + p.z; o.w = o.w * 0.7f + p.w;
  }
  stbf4(out + (size_t)i * HDIM + co, o.x, o.y, o.z, o.w);
}

// ---------------- final dot: out[i] = h[i,:] @ Wf2 + bf2 ----------------
__global__ __launch_bounds__(256) void dot_k(
    const unsigned short* __restrict__ h, const float* __restrict__ w,
    const float* __restrict__ bf2, float* __restrict__ out, int n) {
  int i = blockIdx.x * 4 + (threadIdx.x >> 6);
  int lane = threadIdx.x & 63;
  if (i >= n) return;
  unsigned int hv = *(const unsigned int*)(h + (size_t)i * 128 + lane * 2);
  float2 wv = *(const float2*)(w + lane * 2);
  float p = bf2f(hv & 0xffffu) * wv.x + bf2f(hv >> 16) * wv.y;
#pragma unroll
  for (int off = 1; off < 64; off <<= 1) p += __shfl_xor(p, off);
  if (lane == 0) out[i] = p + bf2[0];
}

extern "C" void kernel_launch(void* const* d_in, const int* in_sizes, int n_in,
                              void* d_out, int out_size, void* d_ws, size_t ws_size,
                              hipStream_t stream) {
  const float* x   = (const float*)d_in[0];
  const int*   ei  = (const int*)d_in[1];
  const float* W1  = (const float*)d_in[2];
  const float* b1  = (const float*)d_in[3];
  const float* g1  = (const float*)d_in[4];
  const float* be1 = (const float*)d_in[5];
  const float* W2  = (const float*)d_in[6];
  const float* b2  = (const float*)d_in[7];
  const float* g2  = (const float*)d_in[8];
  const float* be2 = (const float*)d_in[9];
  const float* W3  = (const float*)d_in[10];
  const float* b3  = (const float*)d_in[11];
  const float* g3  = (const float*)d_in[12];
  const float* be3 = (const float*)d_in[13];
  const float* Wf1 = (const float*)d_in[14];
  const float* bf1 = (const float*)d_in[15];
  const float* Wf2 = (const float*)d_in[16];
  const float* bf2 = (const float*)d_in[17];
  float* out = (float*)d_out;

  const int n = in_sizes[0] / DIN;   // 50000
  const int e = in_sizes[1] / 2;     // 800000
  const int* row = ei;               // sources
  const int* col = ei + e;           // targets

  char* ws = (char*)d_ws;
  size_t off = 0;
  auto alloc = [&](size_t bytes) -> void* {
    void* p = ws + off;
    off = (off + bytes + 255) & ~(size_t)255;
    return p;
  };
  float*          dis     = (float*)alloc((size_t)n * 4);
  int*            deg_i   = (int*)alloc((size_t)n * 4);
  int*            cur     = (int*)alloc((size_t)n * 4);
  int*            row_ptr = (int*)alloc((size_t)(n + 1) * 4);
  int*            srcs    = (int*)alloc((size_t)e * 4);
  unsigned short* W1p     = (unsigned short*)alloc((size_t)DIN * HDIM * 2);
  unsigned short* W2p     = (unsigned short*)alloc((size_t)HDIM * HDIM * 2);
  unsigned short* W3p     = (unsigned short*)alloc((size_t)HDIM * HDIM * 2);
  unsigned short* Wf1p    = (unsigned short*)alloc((size_t)HDIM * 128 * 2);
  unsigned short* xbf     = (unsigned short*)alloc((size_t)n * DIN * 2);
  unsigned short* xws     = (unsigned short*)alloc((size_t)n * HDIM * 2);
  unsigned short* x1      = (unsigned short*)alloc((size_t)n * HDIM * 2);
  unsigned short* x2      = (unsigned short*)alloc((size_t)n * HDIM * 2);
  unsigned short* x3      = x1;    // x1 dead once x2 computed
  unsigned short* h       = xbf;   // xbf dead after GEMM1

  const int nb  = (n + 255) / 256;
  const int eb  = (e + 255) / 256;
  const int lnb = (n + 3) / 4;
  const int gb  = (n + 63) / 64;

  // CSR build + normalization
  zero_i_k<<<nb, 256, 0, stream>>>(deg_i, cur, n);
  hist_k<<<eb, 256, 0, stream>>>(col, deg_i, e);
  fin_k<<<nb, 256, 0, stream>>>(deg_i, dis, n);
  scan_k<<<1, 1024, 0, stream>>>(deg_i, row_ptr, n);
  fill_k<<<eb, 256, 0, stream>>>(row, col, row_ptr, cur, srcs, e);

  // weight packs + input cast
  pack_k<<<(DIN * HDIM + 255) / 256, 256, 0, stream>>>(W1, W1p, DIN, HDIM);
  pack_k<<<(HDIM * HDIM + 255) / 256, 256, 0, stream>>>(W2, W2p, HDIM, HDIM);
  pack_k<<<(HDIM * HDIM + 255) / 256, 256, 0, stream>>>(W3, W3p, HDIM, HDIM);
  pack_k<<<(HDIM * 128 + 255) / 256, 256, 0, stream>>>(Wf1, Wf1p, HDIM, 128);
  cvt_k<<<(n * DIN + 255) / 256, 256, 0, stream>>>(x, xbf, n * DIN);

  // layer 1
  gemm_k<0, DIN, HDIM><<<gb, 256, 0, stream>>>(xbf, W1p, xws, dis, n);
  gather_ln_k<0><<<lnb, 256, 0, stream>>>(xws, row_ptr, srcs, dis, b1, g1, be1, nullptr, x1, n);

  // layer 2
  gemm_k<0, HDIM, HDIM><<<gb, 256, 0, stream>>>(x1, W2p, xws, dis, n);
  gather_ln_k<1><<<lnb, 256, 0, stream>>>(xws, row_ptr, srcs, dis, b2, g2, be2, x1, x2, n);

  // layer 3
  gemm_k<0, HDIM, HDIM><<<gb, 256, 0, stream>>>(x2, W3p, xws, dis, n);
  gather_ln_k<2><<<lnb, 256, 0, stream>>>(xws, row_ptr, srcs, dis, b3, g3, be3, x2, x3, n);

  // MLP head
  gemm_k<1, HDIM, 128><<<gb, 256, 0, stream>>>(x3, Wf1p, h, bf1, n);
  dot_k<<<lnb, 256, 0, stream>>>(h, Wf2, bf2, out, n);
}

// Round 4
// 584.594 us; speedup vs baseline: 14.6566x; 1.1489x over previous
//
#include <hip/hip_runtime.h>
#include <cstdint>
#include <cstddef>

#define HDIM 256
#define DIN 128
#define EPSV 1e-5f
#define SCHUNK 1024

typedef __attribute__((ext_vector_type(8))) short short8;   // 8 bf16 = 4 VGPRs
typedef __attribute__((ext_vector_type(4))) float f32x4;    // MFMA acc

__device__ __forceinline__ float bf2f(unsigned int u16) {
  union { unsigned int i; float f; } v; v.i = u16 << 16; return v.f;
}
__device__ __forceinline__ unsigned short f2bf(float f) {
  union { float f; unsigned int i; } v; v.f = f;
  unsigned int u = v.i;
  return (unsigned short)((u + 0x7fffu + ((u >> 16) & 1u)) >> 16);
}
__device__ __forceinline__ float4 ldbf4(const unsigned short* p) {
  uint2 v = *(const uint2*)p;
  return make_float4(bf2f(v.x & 0xffffu), bf2f(v.x >> 16),
                     bf2f(v.y & 0xffffu), bf2f(v.y >> 16));
}
__device__ __forceinline__ void stbf4(unsigned short* p, float a, float b, float c, float d) {
  uint2 o;
  o.x = (unsigned int)f2bf(a) | ((unsigned int)f2bf(b) << 16);
  o.y = (unsigned int)f2bf(c) | ((unsigned int)f2bf(d) << 16);
  *(uint2*)p = o;
}

// ---------------- CSR build ----------------
__global__ __launch_bounds__(256) void zero_i_k(int* deg, int* cur, int n) {
  int i = blockIdx.x * 256 + threadIdx.x;
  if (i < n) { deg[i] = 0; cur[i] = 0; }
}

__global__ __launch_bounds__(256) void hist_k(const int* __restrict__ col, int* deg, int e) {
  int i = blockIdx.x * 256 + threadIdx.x;
  if (i < e) atomicAdd(&deg[col[i]], 1);
}

// scanA: per-block exclusive scan of 1024 deg entries (4/thread), block total out.
// fused: dis[i] = rsqrt(deg[i]+1)
__global__ __launch_bounds__(256) void scanA_k(const int* __restrict__ deg,
                                               int* __restrict__ row_ptr,
                                               int* __restrict__ blockSums,
                                               float* __restrict__ dis, int n) {
  __shared__ int waveSums[4];
  const int tid = threadIdx.x, lane = tid & 63, w = tid >> 6;
  const int base = blockIdx.x * SCHUNK + tid * 4;
  int v0 = 0, v1 = 0, v2 = 0, v3 = 0;
  if (base + 0 < n) v0 = deg[base + 0];
  if (base + 1 < n) v1 = deg[base + 1];
  if (base + 2 < n) v2 = deg[base + 2];
  if (base + 3 < n) v3 = deg[base + 3];
  if (base + 0 < n) dis[base + 0] = rsqrtf((float)(v0 + 1));
  if (base + 1 < n) dis[base + 1] = rsqrtf((float)(v1 + 1));
  if (base + 2 < n) dis[base + 2] = rsqrtf((float)(v2 + 1));
  if (base + 3 < n) dis[base + 3] = rsqrtf((float)(v3 + 1));
  int tsum = v0 + v1 + v2 + v3;
  int inc = tsum;
#pragma unroll
  for (int off = 1; off < 64; off <<= 1) {
    int t = __shfl_up(inc, off);
    if (lane >= off) inc += t;
  }
  if (lane == 63) waveSums[w] = inc;
  __syncthreads();
  int woff = 0;
#pragma unroll
  for (int k = 0; k < 4; ++k) woff += (k < w) ? waveSums[k] : 0;
  int excl = woff + inc - tsum;
  if (base + 0 < n) row_ptr[base + 0] = excl;
  if (base + 1 < n) row_ptr[base + 1] = excl + v0;
  if (base + 2 < n) row_ptr[base + 2] = excl + v0 + v1;
  if (base + 3 < n) row_ptr[base + 3] = excl + v0 + v1 + v2;
  if (tid == 255) blockSums[blockIdx.x] = woff + inc;
}

// scanB: exclusive scan of nb (<=256) block sums, single block
__global__ __launch_bounds__(256) void scanB_k(int* blockSums, int nb) {
  __shared__ int waveSums[4];
  const int tid = threadIdx.x, lane = tid & 63, w = tid >> 6;
  int v = (tid < nb) ? blockSums[tid] : 0;
  int inc = v;
#pragma unroll
  for (int off = 1; off < 64; off <<= 1) {
    int t = __shfl_up(inc, off);
    if (lane >= off) inc += t;
  }
  if (lane == 63) waveSums[w] = inc;
  __syncthreads();
  int woff = 0;
#pragma unroll
  for (int k = 0; k < 4; ++k) woff += (k < w) ? waveSums[k] : 0;
  if (tid < nb) blockSums[tid] = woff + inc - v;
}

// scanC: add block offsets; thread 0 of block 0 writes row_ptr[n] = e
__global__ __launch_bounds__(256) void scanC_k(int* __restrict__ row_ptr,
                                               const int* __restrict__ blockSums,
                                               int n, int e) {
  const int base = blockIdx.x * SCHUNK + threadIdx.x * 4;
  const int add = blockSums[blockIdx.x];
#pragma unroll
  for (int k = 0; k < 4; ++k)
    if (base + k < n) row_ptr[base + k] += add;
  if (blockIdx.x == 0 && threadIdx.x == 0) row_ptr[n] = e;
}

__global__ __launch_bounds__(256) void fill_k(const int* __restrict__ row,
                                              const int* __restrict__ col,
                                              const int* __restrict__ row_ptr,
                                              int* cur, int* srcs, int e) {
  int i = blockIdx.x * 256 + threadIdx.x;
  if (i < e) {
    int c = col[i];
    int p = row_ptr[c] + atomicAdd(&cur[c], 1);
    srcs[p] = row[i];
  }
}

// ---------------- weight pack: W[K,C] fp32 -> bf16 MFMA A-operand fragments ----
__global__ __launch_bounds__(256) void pack_k(const float* __restrict__ W,
                                              unsigned short* __restrict__ out,
                                              int K, int C) {
  int idx = blockIdx.x * 256 + threadIdx.x;
  if (idx >= K * C) return;
  int j = idx & 7, lane = (idx >> 3) & 63, rest = idx >> 9;
  int NSUB = C >> 4;
  int ns = rest % NSUB, kb = rest / NSUB;
  int k = kb * 32 + (lane >> 4) * 8 + j;
  int c = ns * 16 + (lane & 15);
  out[idx] = f2bf(W[(size_t)k * C + c]);
}

__global__ __launch_bounds__(256) void cvt_k(const float* __restrict__ in,
                                             unsigned short* __restrict__ out, int tot) {
  int i = blockIdx.x * 256 + threadIdx.x;
  if (i < tot) out[i] = f2bf(in[i]);
}

// ---------------- bf16 MFMA GEMM (swapped operands) ----------------
template<int MODE, int K, int CN>
__global__ __launch_bounds__(256) void gemm_k(
    const unsigned short* __restrict__ A, const unsigned short* __restrict__ Wp,
    unsigned short* __restrict__ out, const float* __restrict__ sb, int n) {
  constexpr int NSUB = CN / 16;
  const int t = threadIdx.x;
  const int w = t >> 6, lane = t & 63;
  const int g = lane >> 4, i = lane & 15;
  const int mrow = blockIdx.x * 64 + w * 16 + i;
  const int mload = mrow < n ? mrow : n - 1;

  f32x4 acc[NSUB];
#pragma unroll
  for (int ns = 0; ns < NSUB; ++ns) acc[ns] = (f32x4){0.f, 0.f, 0.f, 0.f};

  const unsigned short* arow = A + (size_t)mload * K + g * 8;
#pragma unroll 2
  for (int kc = 0; kc < K / 32; ++kc) {
    short8 af = *(const short8*)(arow + kc * 32);
    const short8* wp = (const short8*)(Wp) + (size_t)(kc * NSUB) * 64 + lane;
#pragma unroll
    for (int ns = 0; ns < NSUB; ++ns) {
      short8 wf = wp[ns * 64];
      acc[ns] = __builtin_amdgcn_mfma_f32_16x16x32_bf16(wf, af, acc[ns], 0, 0, 0);
    }
  }

  if (mrow < n) {
    unsigned short* op = out + (size_t)mrow * CN + g * 4;
    if (MODE == 0) {
      float s = sb[mrow];
#pragma unroll
      for (int ns = 0; ns < NSUB; ++ns)
        stbf4(op + ns * 16, acc[ns][0] * s, acc[ns][1] * s, acc[ns][2] * s, acc[ns][3] * s);
    } else {
#pragma unroll
      for (int ns = 0; ns < NSUB; ++ns) {
        float4 b4 = *(const float4*)(sb + ns * 16 + g * 4);
        stbf4(op + ns * 16,
              fmaxf(acc[ns][0] + b4.x, 0.f), fmaxf(acc[ns][1] + b4.y, 0.f),
              fmaxf(acc[ns][2] + b4.z, 0.f), fmaxf(acc[ns][3] + b4.w, 0.f));
      }
    }
  }
}

// ---------------- fused gather + bias + LayerNorm + ReLU + residual (bf16 io) ----
template<int MODE>
__global__ __launch_bounds__(256) void gather_ln_k(
    const unsigned short* __restrict__ xws, const int* __restrict__ row_ptr,
    const int* __restrict__ srcs, const float* __restrict__ dis,
    const float* __restrict__ bias, const float* __restrict__ g,
    const float* __restrict__ be, const unsigned short* __restrict__ xprev,
    unsigned short* __restrict__ out, int n) {
  int i = blockIdx.x * 4 + (threadIdx.x >> 6);
  int lane = threadIdx.x & 63;
  if (i >= n) return;
  int beg = row_ptr[i], end = row_ptr[i + 1];
  const int co = lane * 4;
  float4 acc = ldbf4(xws + (size_t)i * HDIM + co);  // self-loop
  int j = beg;
  for (; j + 8 <= end; j += 8) {
    int r0 = srcs[j], r1 = srcs[j + 1], r2 = srcs[j + 2], r3 = srcs[j + 3];
    int r4 = srcs[j + 4], r5 = srcs[j + 5], r6 = srcs[j + 6], r7 = srcs[j + 7];
    float4 v0 = ldbf4(xws + (size_t)r0 * HDIM + co);
    float4 v1 = ldbf4(xws + (size_t)r1 * HDIM + co);
    float4 v2 = ldbf4(xws + (size_t)r2 * HDIM + co);
    float4 v3 = ldbf4(xws + (size_t)r3 * HDIM + co);
    float4 v4 = ldbf4(xws + (size_t)r4 * HDIM + co);
    float4 v5 = ldbf4(xws + (size_t)r5 * HDIM + co);
    float4 v6 = ldbf4(xws + (size_t)r6 * HDIM + co);
    float4 v7 = ldbf4(xws + (size_t)r7 * HDIM + co);
    acc.x += ((v0.x + v1.x) + (v2.x + v3.x)) + ((v4.x + v5.x) + (v6.x + v7.x));
    acc.y += ((v0.y + v1.y) + (v2.y + v3.y)) + ((v4.y + v5.y) + (v6.y + v7.y));
    acc.z += ((v0.z + v1.z) + (v2.z + v3.z)) + ((v4.z + v5.z) + (v6.z + v7.z));
    acc.w += ((v0.w + v1.w) + (v2.w + v3.w)) + ((v4.w + v5.w) + (v6.w + v7.w));
  }
  for (; j + 4 <= end; j += 4) {
    int r0 = srcs[j], r1 = srcs[j + 1], r2 = srcs[j + 2], r3 = srcs[j + 3];
    float4 v0 = ldbf4(xws + (size_t)r0 * HDIM + co);
    float4 v1 = ldbf4(xws + (size_t)r1 * HDIM + co);
    float4 v2 = ldbf4(xws + (size_t)r2 * HDIM + co);
    float4 v3 = ldbf4(xws + (size_t)r3 * HDIM + co);
    acc.x += (v0.x + v1.x) + (v2.x + v3.x);
    acc.y += (v0.y + v1.y) + (v2.y + v3.y);
    acc.z += (v0.z + v1.z) + (v2.z + v3.z);
    acc.w += (v0.w + v1.w) + (v2.w + v3.w);
  }
  for (; j < end; ++j) {
    float4 v = ldbf4(xws + (size_t)srcs[j] * HDIM + co);
    acc.x += v.x; acc.y += v.y; acc.z += v.z; acc.w += v.w;
  }
  float di = dis[i];
  float4 b4 = *(const float4*)(bias + co);
  float4 v;
  v.x = acc.x * di + b4.x;
  v.y = acc.y * di + b4.y;
  v.z = acc.z * di + b4.z;
  v.w = acc.w * di + b4.w;
  float s = v.x + v.y + v.z + v.w;
  float s2 = v.x * v.x + v.y * v.y + v.z * v.z + v.w * v.w;
#pragma unroll
  for (int off = 1; off < 64; off <<= 1) {
    s += __shfl_xor(s, off);
    s2 += __shfl_xor(s2, off);
  }
  float mu = s * (1.f / HDIM);
  float inv = rsqrtf(s2 * (1.f / HDIM) - mu * mu + EPSV);
  float4 g4 = *(const float4*)(g + co);
  float4 e4 = *(const float4*)(be + co);
  float4 o;
  o.x = fmaxf((v.x - mu) * inv * g4.x + e4.x, 0.f);
  o.y = fmaxf((v.y - mu) * inv * g4.y + e4.y, 0.f);
  o.z = fmaxf((v.z - mu) * inv * g4.z + e4.z, 0.f);
  o.w = fmaxf((v.w - mu) * inv * g4.w + e4.w, 0.f);
  if (MODE == 1) {
    float4 p = ldbf4(xprev + (size_t)i * HDIM + co);
    o.x += 0.7f * p.x; o.y += 0.7f * p.y; o.z += 0.7f * p.z; o.w += 0.7f * p.w;
  } else if (MODE == 2) {
    float4 p = ldbf4(xprev + (size_t)i * HDIM + co);
    o.x = o.x * 0.7f + p.x; o.y = o.y * 0.7f + p.y;
    o.z = o.z * 0.7f + p.z; o.w = o.w * 0.7f + p.w;
  }
  stbf4(out + (size_t)i * HDIM + co, o.x, o.y, o.z, o.w);
}

// ---------------- final dot: out[i] = h[i,:] @ Wf2 + bf2 ----------------
__global__ __launch_bounds__(256) void dot_k(
    const unsigned short* __restrict__ h, const float* __restrict__ w,
    const float* __restrict__ bf2, float* __restrict__ out, int n) {
  int i = blockIdx.x * 4 + (threadIdx.x >> 6);
  int lane = threadIdx.x & 63;
  if (i >= n) return;
  unsigned int hv = *(const unsigned int*)(h + (size_t)i * 128 + lane * 2);
  float2 wv = *(const float2*)(w + lane * 2);
  float p = bf2f(hv & 0xffffu) * wv.x + bf2f(hv >> 16) * wv.y;
#pragma unroll
  for (int off = 1; off < 64; off <<= 1) p += __shfl_xor(p, off);
  if (lane == 0) out[i] = p + bf2[0];
}

extern "C" void kernel_launch(void* const* d_in, const int* in_sizes, int n_in,
                              void* d_out, int out_size, void* d_ws, size_t ws_size,
                              hipStream_t stream) {
  const float* x   = (const float*)d_in[0];
  const int*   ei  = (const int*)d_in[1];
  const float* W1  = (const float*)d_in[2];
  const float* b1  = (const float*)d_in[3];
  const float* g1  = (const float*)d_in[4];
  const float* be1 = (const float*)d_in[5];
  const float* W2  = (const float*)d_in[6];
  const float* b2  = (const float*)d_in[7];
  const float* g2  = (const float*)d_in[8];
  const float* be2 = (const float*)d_in[9];
  const float* W3  = (const float*)d_in[10];
  const float* b3  = (const float*)d_in[11];
  const float* g3  = (const float*)d_in[12];
  const float* be3 = (const float*)d_in[13];
  const float* Wf1 = (const float*)d_in[14];
  const float* bf1 = (const float*)d_in[15];
  const float* Wf2 = (const float*)d_in[16];
  const float* bf2 = (const float*)d_in[17];
  float* out = (float*)d_out;

  const int n = in_sizes[0] / DIN;   // 50000
  const int e = in_sizes[1] / 2;     // 800000
  const int* row = ei;               // sources
  const int* col = ei + e;           // targets

  char* ws = (char*)d_ws;
  size_t off = 0;
  auto alloc = [&](size_t bytes) -> void* {
    void* p = ws + off;
    off = (off + bytes + 255) & ~(size_t)255;
    return p;
  };
  float*          dis     = (float*)alloc((size_t)n * 4);
  int*            deg_i   = (int*)alloc((size_t)n * 4);
  int*            cur     = (int*)alloc((size_t)n * 4);
  int*            row_ptr = (int*)alloc((size_t)(n + 1) * 4);
  int*            bsums   = (int*)alloc((size_t)256 * 4);
  int*            srcs    = (int*)alloc((size_t)e * 4);
  unsigned short* W1p     = (unsigned short*)alloc((size_t)DIN * HDIM * 2);
  unsigned short* W2p     = (unsigned short*)alloc((size_t)HDIM * HDIM * 2);
  unsigned short* W3p     = (unsigned short*)alloc((size_t)HDIM * HDIM * 2);
  unsigned short* Wf1p    = (unsigned short*)alloc((size_t)HDIM * 128 * 2);
  unsigned short* xbf     = (unsigned short*)alloc((size_t)n * DIN * 2);
  unsigned short* xws     = (unsigned short*)alloc((size_t)n * HDIM * 2);
  unsigned short* x1      = (unsigned short*)alloc((size_t)n * HDIM * 2);
  unsigned short* x2      = (unsigned short*)alloc((size_t)n * HDIM * 2);
  unsigned short* x3      = x1;    // x1 dead once x2 computed
  unsigned short* h       = xbf;   // xbf dead after GEMM1

  const int nb  = (n + 255) / 256;
  const int eb  = (e + 255) / 256;
  const int lnb = (n + 3) / 4;
  const int gb  = (n + 63) / 64;
  const int sb_ = (n + SCHUNK - 1) / SCHUNK;  // scan blocks (49)

  // CSR build + normalization (two-level parallel scan, dis fused into scanA)
  zero_i_k<<<nb, 256, 0, stream>>>(deg_i, cur, n);
  hist_k<<<eb, 256, 0, stream>>>(col, deg_i, e);
  scanA_k<<<sb_, 256, 0, stream>>>(deg_i, row_ptr, bsums, dis, n);
  scanB_k<<<1, 256, 0, stream>>>(bsums, sb_);
  scanC_k<<<sb_, 256, 0, stream>>>(row_ptr, bsums, n, e);
  fill_k<<<eb, 256, 0, stream>>>(row, col, row_ptr, cur, srcs, e);

  // weight packs + input cast
  pack_k<<<(DIN * HDIM + 255) / 256, 256, 0, stream>>>(W1, W1p, DIN, HDIM);
  pack_k<<<(HDIM * HDIM + 255) / 256, 256, 0, stream>>>(W2, W2p, HDIM, HDIM);
  pack_k<<<(HDIM * HDIM + 255) / 256, 256, 0, stream>>>(W3, W3p, HDIM, HDIM);
  pack_k<<<(HDIM * 128 + 255) / 256, 256, 0, stream>>>(Wf1, Wf1p, HDIM, 128);
  cvt_k<<<(n * DIN + 255) / 256, 256, 0, stream>>>(x, xbf, n * DIN);

  // layer 1
  gemm_k<0, DIN, HDIM><<<gb, 256, 0, stream>>>(xbf, W1p, xws, dis, n);
  gather_ln_k<0><<<lnb, 256, 0, stream>>>(xws, row_ptr, srcs, dis, b1, g1, be1, nullptr, x1, n);

  // layer 2
  gemm_k<0, HDIM, HDIM><<<gb, 256, 0, stream>>>(x1, W2p, xws, dis, n);
  gather_ln_k<1><<<lnb, 256, 0, stream>>>(xws, row_ptr, srcs, dis, b2, g2, be2, x1, x2, n);

  // layer 3
  gemm_k<0, HDIM, HDIM><<<gb, 256, 0, stream>>>(x2, W3p, xws, dis, n);
  gather_ln_k<2><<<lnb, 256, 0, stream>>>(xws, row_ptr, srcs, dis, b3, g3, be3, x2, x3, n);

  // MLP head
  gemm_k<1, HDIM, 128><<<gb, 256, 0, stream>>>(x3, Wf1p, h, bf1, n);
  dot_k<<<lnb, 256, 0, stream>>>(h, Wf2, bf2, out, n);
}

// Round 5
// 486.249 us; speedup vs baseline: 17.6209x; 1.2023x over previous
//
#include <hip/hip_runtime.h>
#include <cstdint>
#include <cstddef>

#define HDIM 256
#define DIN 128
#define EPSV 1e-5f
#define SCHUNK 1024

typedef __attribute__((ext_vector_type(8))) short short8;   // 8 bf16 = 4 VGPRs
typedef __attribute__((ext_vector_type(4))) float f32x4;    // MFMA acc

__device__ __forceinline__ float bf2f(unsigned int u16) {
  union { unsigned int i; float f; } v; v.i = u16 << 16; return v.f;
}
__device__ __forceinline__ unsigned short f2bf(float f) {
  union { float f; unsigned int i; } v; v.f = f;
  unsigned int u = v.i;
  return (unsigned short)((u + 0x7fffu + ((u >> 16) & 1u)) >> 16);
}
__device__ __forceinline__ float4 ldbf4(const unsigned short* p) {
  uint2 v = *(const uint2*)p;
  return make_float4(bf2f(v.x & 0xffffu), bf2f(v.x >> 16),
                     bf2f(v.y & 0xffffu), bf2f(v.y >> 16));
}
__device__ __forceinline__ void stbf4(unsigned short* p, float a, float b, float c, float d) {
  uint2 o;
  o.x = (unsigned int)f2bf(a) | ((unsigned int)f2bf(b) << 16);
  o.y = (unsigned int)f2bf(c) | ((unsigned int)f2bf(d) << 16);
  *(uint2*)p = o;
}

// ---------------- CSR build ----------------
__global__ __launch_bounds__(256) void zero_i_k(int* deg, int* cur, int n) {
  int i = blockIdx.x * 256 + threadIdx.x;
  if (i < n) { deg[i] = 0; cur[i] = 0; }
}

__global__ __launch_bounds__(256) void hist_k(const int* __restrict__ col, int* deg, int e) {
  int i = blockIdx.x * 256 + threadIdx.x;
  if (i < e) atomicAdd(&deg[col[i]], 1);
}

// scanA: per-block exclusive scan of 1024 deg entries (4/thread); fused dis=rsqrt(deg+1)
__global__ __launch_bounds__(256) void scanA_k(const int* __restrict__ deg,
                                               int* __restrict__ row_ptr,
                                               int* __restrict__ blockSums,
                                               float* __restrict__ dis, int n) {
  __shared__ int waveSums[4];
  const int tid = threadIdx.x, lane = tid & 63, w = tid >> 6;
  const int base = blockIdx.x * SCHUNK + tid * 4;
  int v0 = 0, v1 = 0, v2 = 0, v3 = 0;
  if (base + 0 < n) v0 = deg[base + 0];
  if (base + 1 < n) v1 = deg[base + 1];
  if (base + 2 < n) v2 = deg[base + 2];
  if (base + 3 < n) v3 = deg[base + 3];
  if (base + 0 < n) dis[base + 0] = rsqrtf((float)(v0 + 1));
  if (base + 1 < n) dis[base + 1] = rsqrtf((float)(v1 + 1));
  if (base + 2 < n) dis[base + 2] = rsqrtf((float)(v2 + 1));
  if (base + 3 < n) dis[base + 3] = rsqrtf((float)(v3 + 1));
  int tsum = v0 + v1 + v2 + v3;
  int inc = tsum;
#pragma unroll
  for (int off = 1; off < 64; off <<= 1) {
    int t = __shfl_up(inc, off);
    if (lane >= off) inc += t;
  }
  if (lane == 63) waveSums[w] = inc;
  __syncthreads();
  int woff = 0;
#pragma unroll
  for (int k = 0; k < 4; ++k) woff += (k < w) ? waveSums[k] : 0;
  int excl = woff + inc - tsum;
  if (base + 0 < n) row_ptr[base + 0] = excl;
  if (base + 1 < n) row_ptr[base + 1] = excl + v0;
  if (base + 2 < n) row_ptr[base + 2] = excl + v0 + v1;
  if (base + 3 < n) row_ptr[base + 3] = excl + v0 + v1 + v2;
  if (tid == 255) blockSums[blockIdx.x] = woff + inc;
}

__global__ __launch_bounds__(256) void scanB_k(int* blockSums, int nb) {
  __shared__ int waveSums[4];
  const int tid = threadIdx.x, lane = tid & 63, w = tid >> 6;
  int v = (tid < nb) ? blockSums[tid] : 0;
  int inc = v;
#pragma unroll
  for (int off = 1; off < 64; off <<= 1) {
    int t = __shfl_up(inc, off);
    if (lane >= off) inc += t;
  }
  if (lane == 63) waveSums[w] = inc;
  __syncthreads();
  int woff = 0;
#pragma unroll
  for (int k = 0; k < 4; ++k) woff += (k < w) ? waveSums[k] : 0;
  if (tid < nb) blockSums[tid] = woff + inc - v;
}

__global__ __launch_bounds__(256) void scanC_k(int* __restrict__ row_ptr,
                                               const int* __restrict__ blockSums,
                                               int n, int e) {
  const int base = blockIdx.x * SCHUNK + threadIdx.x * 4;
  const int add = blockSums[blockIdx.x];
#pragma unroll
  for (int k = 0; k < 4; ++k)
    if (base + k < n) row_ptr[base + k] += add;
  if (blockIdx.x == 0 && threadIdx.x == 0) row_ptr[n] = e;
}

__global__ __launch_bounds__(256) void fill_k(const int* __restrict__ row,
                                              const int* __restrict__ col,
                                              const int* __restrict__ row_ptr,
                                              int* cur, int* srcs, int e) {
  int i = blockIdx.x * 256 + threadIdx.x;
  if (i < e) {
    int c = col[i];
    int p = row_ptr[c] + atomicAdd(&cur[c], 1);
    srcs[p] = row[i];
  }
}

// ---------------- weight pack: W[K,C] fp32 -> bf16 MFMA A-operand fragments ----
// layout: [kb][ns][lane][j]; value = W[kb*32 + (lane>>4)*8 + j][ns*16 + (lane&15)]
__global__ __launch_bounds__(256) void pack_k(const float* __restrict__ W,
                                              unsigned short* __restrict__ out,
                                              int K, int C) {
  int idx = blockIdx.x * 256 + threadIdx.x;
  if (idx >= K * C) return;
  int j = idx & 7, lane = (idx >> 3) & 63, rest = idx >> 9;
  int NSUB = C >> 4;
  int ns = rest % NSUB, kb = rest / NSUB;
  int k = kb * 32 + (lane >> 4) * 8 + j;
  int c = ns * 16 + (lane & 15);
  out[idx] = f2bf(W[(size_t)k * C + c]);
}

__global__ __launch_bounds__(256) void cvt_k(const float* __restrict__ in,
                                             unsigned short* __restrict__ out, int tot) {
  int i = blockIdx.x * 256 + threadIdx.x;
  if (i < tot) out[i] = f2bf(in[i]);
}

// ---------------- bf16 MFMA GEMM, wave tile = 32 rows x 64 cols ----------------
// block = 4 waves = 64 rows x 128 cols; grid = (ceil(n/64), CN/128)
// swapped operands: mfma(wf, af) -> lane holds cols [ns*16 + g*4 .. +3] of row (i).
// register double-buffer prefetch over K-chunks of 32.
template<int MODE, int K, int CN>
__global__ __launch_bounds__(256) void gemm_k(
    const unsigned short* __restrict__ A, const unsigned short* __restrict__ Wp,
    unsigned short* __restrict__ out, const float* __restrict__ sb, int n) {
  constexpr int NSUB = CN / 16;
  constexpr int KC = K / 32;
  const int t = threadIdx.x;
  const int w = t >> 6, lane = t & 63;
  const int rg = w & 1, cg = w >> 1;
  const int g = lane >> 4, i = lane & 15;
  const int m0 = blockIdx.x * 64 + rg * 32;
  const int nsBase = blockIdx.y * 8 + cg * 4;

  const int r0 = m0 + i, r1 = m0 + 16 + i;
  const int l0 = r0 < n ? r0 : n - 1;
  const int l1 = r1 < n ? r1 : n - 1;
  const unsigned short* a0 = A + (size_t)l0 * K + g * 8;
  const unsigned short* a1 = A + (size_t)l1 * K + g * 8;
  const short8* wp = (const short8*)Wp + (size_t)nsBase * 64 + lane;

  f32x4 acc[2][4];
#pragma unroll
  for (int rr = 0; rr < 2; ++rr)
#pragma unroll
    for (int j = 0; j < 4; ++j) acc[rr][j] = (f32x4){0.f, 0.f, 0.f, 0.f};

  short8 af0 = *(const short8*)a0;
  short8 af1 = *(const short8*)a1;
  short8 wf[4];
#pragma unroll
  for (int j = 0; j < 4; ++j) wf[j] = wp[j * 64];

#pragma unroll
  for (int kc = 0; kc < KC; ++kc) {
    short8 naf0, naf1, nwf[4];
    if (kc + 1 < KC) {
      naf0 = *(const short8*)(a0 + (kc + 1) * 32);
      naf1 = *(const short8*)(a1 + (kc + 1) * 32);
#pragma unroll
      for (int j = 0; j < 4; ++j) nwf[j] = wp[(size_t)(kc + 1) * NSUB * 64 + j * 64];
    }
#pragma unroll
    for (int j = 0; j < 4; ++j) {
      acc[0][j] = __builtin_amdgcn_mfma_f32_16x16x32_bf16(wf[j], af0, acc[0][j], 0, 0, 0);
      acc[1][j] = __builtin_amdgcn_mfma_f32_16x16x32_bf16(wf[j], af1, acc[1][j], 0, 0, 0);
    }
    if (kc + 1 < KC) {
      af0 = naf0; af1 = naf1;
#pragma unroll
      for (int j = 0; j < 4; ++j) wf[j] = nwf[j];
    }
  }

#pragma unroll
  for (int rr = 0; rr < 2; ++rr) {
    int r = m0 + rr * 16 + i;
    if (r < n) {
      unsigned short* op = out + (size_t)r * CN + nsBase * 16 + g * 4;
      if (MODE == 0) {
        float s = sb[r];
#pragma unroll
        for (int j = 0; j < 4; ++j)
          stbf4(op + j * 16, acc[rr][j][0] * s, acc[rr][j][1] * s,
                acc[rr][j][2] * s, acc[rr][j][3] * s);
      } else {
#pragma unroll
        for (int j = 0; j < 4; ++j) {
          float4 b4 = *(const float4*)(sb + nsBase * 16 + j * 16 + g * 4);
          stbf4(op + j * 16,
                fmaxf(acc[rr][j][0] + b4.x, 0.f), fmaxf(acc[rr][j][1] + b4.y, 0.f),
                fmaxf(acc[rr][j][2] + b4.z, 0.f), fmaxf(acc[rr][j][3] + b4.w, 0.f));
        }
      }
    }
  }
}

// ---------------- fused gather + bias + LayerNorm + ReLU + residual (bf16 io) ----
template<int MODE>
__global__ __launch_bounds__(256) void gather_ln_k(
    const unsigned short* __restrict__ xws, const int* __restrict__ row_ptr,
    const int* __restrict__ srcs, const float* __restrict__ dis,
    const float* __restrict__ bias, const float* __restrict__ g,
    const float* __restrict__ be, const unsigned short* __restrict__ xprev,
    unsigned short* __restrict__ out, int n) {
  int i = blockIdx.x * 4 + (threadIdx.x >> 6);
  int lane = threadIdx.x & 63;
  if (i >= n) return;
  int beg = row_ptr[i], end = row_ptr[i + 1];
  const int co = lane * 4;
  float4 acc = ldbf4(xws + (size_t)i * HDIM + co);  // self-loop
  int j = beg;
  for (; j + 8 <= end; j += 8) {
    int r0 = srcs[j], r1 = srcs[j + 1], r2 = srcs[j + 2], r3 = srcs[j + 3];
    int r4 = srcs[j + 4], r5 = srcs[j + 5], r6 = srcs[j + 6], r7 = srcs[j + 7];
    float4 v0 = ldbf4(xws + (size_t)r0 * HDIM + co);
    float4 v1 = ldbf4(xws + (size_t)r1 * HDIM + co);
    float4 v2 = ldbf4(xws + (size_t)r2 * HDIM + co);
    float4 v3 = ldbf4(xws + (size_t)r3 * HDIM + co);
    float4 v4 = ldbf4(xws + (size_t)r4 * HDIM + co);
    float4 v5 = ldbf4(xws + (size_t)r5 * HDIM + co);
    float4 v6 = ldbf4(xws + (size_t)r6 * HDIM + co);
    float4 v7 = ldbf4(xws + (size_t)r7 * HDIM + co);
    acc.x += ((v0.x + v1.x) + (v2.x + v3.x)) + ((v4.x + v5.x) + (v6.x + v7.x));
    acc.y += ((v0.y + v1.y) + (v2.y + v3.y)) + ((v4.y + v5.y) + (v6.y + v7.y));
    acc.z += ((v0.z + v1.z) + (v2.z + v3.z)) + ((v4.z + v5.z) + (v6.z + v7.z));
    acc.w += ((v0.w + v1.w) + (v2.w + v3.w)) + ((v4.w + v5.w) + (v6.w + v7.w));
  }
  for (; j + 4 <= end; j += 4) {
    int r0 = srcs[j], r1 = srcs[j + 1], r2 = srcs[j + 2], r3 = srcs[j + 3];
    float4 v0 = ldbf4(xws + (size_t)r0 * HDIM + co);
    float4 v1 = ldbf4(xws + (size_t)r1 * HDIM + co);
    float4 v2 = ldbf4(xws + (size_t)r2 * HDIM + co);
    float4 v3 = ldbf4(xws + (size_t)r3 * HDIM + co);
    acc.x += (v0.x + v1.x) + (v2.x + v3.x);
    acc.y += (v0.y + v1.y) + (v2.y + v3.y);
    acc.z += (v0.z + v1.z) + (v2.z + v3.z);
    acc.w += (v0.w + v1.w) + (v2.w + v3.w);
  }
  for (; j < end; ++j) {
    float4 v = ldbf4(xws + (size_t)srcs[j] * HDIM + co);
    acc.x += v.x; acc.y += v.y; acc.z += v.z; acc.w += v.w;
  }
  float di = dis[i];
  float4 b4 = *(const float4*)(bias + co);
  float4 v;
  v.x = acc.x * di + b4.x;
  v.y = acc.y * di + b4.y;
  v.z = acc.z * di + b4.z;
  v.w = acc.w * di + b4.w;
  float s = v.x + v.y + v.z + v.w;
  float s2 = v.x * v.x + v.y * v.y + v.z * v.z + v.w * v.w;
#pragma unroll
  for (int off = 1; off < 64; off <<= 1) {
    s += __shfl_xor(s, off);
    s2 += __shfl_xor(s2, off);
  }
  float mu = s * (1.f / HDIM);
  float inv = rsqrtf(s2 * (1.f / HDIM) - mu * mu + EPSV);
  float4 g4 = *(const float4*)(g + co);
  float4 e4 = *(const float4*)(be + co);
  float4 o;
  o.x = fmaxf((v.x - mu) * inv * g4.x + e4.x, 0.f);
  o.y = fmaxf((v.y - mu) * inv * g4.y + e4.y, 0.f);
  o.z = fmaxf((v.z - mu) * inv * g4.z + e4.z, 0.f);
  o.w = fmaxf((v.w - mu) * inv * g4.w + e4.w, 0.f);
  if (MODE == 1) {
    float4 p = ldbf4(xprev + (size_t)i * HDIM + co);
    o.x += 0.7f * p.x; o.y += 0.7f * p.y; o.z += 0.7f * p.z; o.w += 0.7f * p.w;
  } else if (MODE == 2) {
    float4 p = ldbf4(xprev + (size_t)i * HDIM + co);
    o.x = o.x * 0.7f + p.x; o.y = o.y * 0.7f + p.y;
    o.z = o.z * 0.7f + p.z; o.w = o.w * 0.7f + p.w;
  }
  stbf4(out + (size_t)i * HDIM + co, o.x, o.y, o.z, o.w);
}

// ---------------- final dot: out[i] = h[i,:] @ Wf2 + bf2 ----------------
__global__ __launch_bounds__(256) void dot_k(
    const unsigned short* __restrict__ h, const float* __restrict__ w,
    const float* __restrict__ bf2, float* __restrict__ out, int n) {
  int i = blockIdx.x * 4 + (threadIdx.x >> 6);
  int lane = threadIdx.x & 63;
  if (i >= n) return;
  unsigned int hv = *(const unsigned int*)(h + (size_t)i * 128 + lane * 2);
  float2 wv = *(const float2*)(w + lane * 2);
  float p = bf2f(hv & 0xffffu) * wv.x + bf2f(hv >> 16) * wv.y;
#pragma unroll
  for (int off = 1; off < 64; off <<= 1) p += __shfl_xor(p, off);
  if (lane == 0) out[i] = p + bf2[0];
}

extern "C" void kernel_launch(void* const* d_in, const int* in_sizes, int n_in,
                              void* d_out, int out_size, void* d_ws, size_t ws_size,
                              hipStream_t stream) {
  const float* x   = (const float*)d_in[0];
  const int*   ei  = (const int*)d_in[1];
  const float* W1  = (const float*)d_in[2];
  const float* b1  = (const float*)d_in[3];
  const float* g1  = (const float*)d_in[4];
  const float* be1 = (const float*)d_in[5];
  const float* W2  = (const float*)d_in[6];
  const float* b2  = (const float*)d_in[7];
  const float* g2  = (const float*)d_in[8];
  const float* be2 = (const float*)d_in[9];
  const float* W3  = (const float*)d_in[10];
  const float* b3  = (const float*)d_in[11];
  const float* g3  = (const float*)d_in[12];
  const float* be3 = (const float*)d_in[13];
  const float* Wf1 = (const float*)d_in[14];
  const float* bf1 = (const float*)d_in[15];
  const float* Wf2 = (const float*)d_in[16];
  const float* bf2 = (const float*)d_in[17];
  float* out = (float*)d_out;

  const int n = in_sizes[0] / DIN;   // 50000
  const int e = in_sizes[1] / 2;     // 800000
  const int* row = ei;               // sources
  const int* col = ei + e;           // targets

  char* ws = (char*)d_ws;
  size_t off = 0;
  auto alloc = [&](size_t bytes) -> void* {
    void* p = ws + off;
    off = (off + bytes + 255) & ~(size_t)255;
    return p;
  };
  float*          dis     = (float*)alloc((size_t)n * 4);
  int*            deg_i   = (int*)alloc((size_t)n * 4);
  int*            cur     = (int*)alloc((size_t)n * 4);
  int*            row_ptr = (int*)alloc((size_t)(n + 1) * 4);
  int*            bsums   = (int*)alloc((size_t)256 * 4);
  int*            srcs    = (int*)alloc((size_t)e * 4);
  unsigned short* W1p     = (unsigned short*)alloc((size_t)DIN * HDIM * 2);
  unsigned short* W2p     = (unsigned short*)alloc((size_t)HDIM * HDIM * 2);
  unsigned short* W3p     = (unsigned short*)alloc((size_t)HDIM * HDIM * 2);
  unsigned short* Wf1p    = (unsigned short*)alloc((size_t)HDIM * 128 * 2);
  unsigned short* xbf     = (unsigned short*)alloc((size_t)n * DIN * 2);
  unsigned short* xws     = (unsigned short*)alloc((size_t)n * HDIM * 2);
  unsigned short* x1      = (unsigned short*)alloc((size_t)n * HDIM * 2);
  unsigned short* x2      = (unsigned short*)alloc((size_t)n * HDIM * 2);
  unsigned short* x3      = x1;    // x1 dead once x2 computed
  unsigned short* h       = xbf;   // xbf dead after GEMM1

  const int nb  = (n + 255) / 256;
  const int eb  = (e + 255) / 256;
  const int lnb = (n + 3) / 4;
  const int sb_ = (n + SCHUNK - 1) / SCHUNK;
  dim3 gg((n + 63) / 64, 2);   // CN=256: 2 col-blocks of 128
  dim3 gh((n + 63) / 64, 1);   // CN=128

  // CSR build + normalization
  zero_i_k<<<nb, 256, 0, stream>>>(deg_i, cur, n);
  hist_k<<<eb, 256, 0, stream>>>(col, deg_i, e);
  scanA_k<<<sb_, 256, 0, stream>>>(deg_i, row_ptr, bsums, dis, n);
  scanB_k<<<1, 256, 0, stream>>>(bsums, sb_);
  scanC_k<<<sb_, 256, 0, stream>>>(row_ptr, bsums, n, e);
  fill_k<<<eb, 256, 0, stream>>>(row, col, row_ptr, cur, srcs, e);

  // weight packs + input cast
  pack_k<<<(DIN * HDIM + 255) / 256, 256, 0, stream>>>(W1, W1p, DIN, HDIM);
  pack_k<<<(HDIM * HDIM + 255) / 256, 256, 0, stream>>>(W2, W2p, HDIM, HDIM);
  pack_k<<<(HDIM * HDIM + 255) / 256, 256, 0, stream>>>(W3, W3p, HDIM, HDIM);
  pack_k<<<(HDIM * 128 + 255) / 256, 256, 0, stream>>>(Wf1, Wf1p, HDIM, 128);
  cvt_k<<<(n * DIN + 255) / 256, 256, 0, stream>>>(x, xbf, n * DIN);

  // layer 1
  gemm_k<0, DIN, HDIM><<<gg, 256, 0, stream>>>(xbf, W1p, xws, dis, n);
  gather_ln_k<0><<<lnb, 256, 0, stream>>>(xws, row_ptr, srcs, dis, b1, g1, be1, nullptr, x1, n);

  // layer 2
  gemm_k<0, HDIM, HDIM><<<gg, 256, 0, stream>>>(x1, W2p, xws, dis, n);
  gather_ln_k<1><<<lnb, 256, 0, stream>>>(xws, row_ptr, srcs, dis, b2, g2, be2, x1, x2, n);

  // layer 3
  gemm_k<0, HDIM, HDIM><<<gg, 256, 0, stream>>>(x2, W3p, xws, dis, n);
  gather_ln_k<2><<<lnb, 256, 0, stream>>>(xws, row_ptr, srcs, dis, b3, g3, be3, x2, x3, n);

  // MLP head
  gemm_k<1, HDIM, 128><<<gh, 256, 0, stream>>>(x3, Wf1p, h, bf1, n);
  dot_k<<<lnb, 256, 0, stream>>>(h, Wf2, bf2, out, n);
}

// Round 6
// 470.564 us; speedup vs baseline: 18.2083x; 1.0333x over previous
//
#include <hip/hip_runtime.h>
#include <cstdint>
#include <cstddef>

#define HDIM 256
#define DIN 128
#define EPSV 1e-5f
#define SCHUNK 1024

typedef __attribute__((ext_vector_type(8))) short short8;   // 8 bf16 = 4 VGPRs
typedef __attribute__((ext_vector_type(4))) float f32x4;    // MFMA acc

__device__ __forceinline__ float bf2f(unsigned int u16) {
  union { unsigned int i; float f; } v; v.i = u16 << 16; return v.f;
}
__device__ __forceinline__ unsigned short f2bf(float f) {
  union { float f; unsigned int i; } v; v.f = f;
  unsigned int u = v.i;
  return (unsigned short)((u + 0x7fffu + ((u >> 16) & 1u)) >> 16);
}
__device__ __forceinline__ float4 ldbf4(const unsigned short* p) {
  uint2 v = *(const uint2*)p;
  return make_float4(bf2f(v.x & 0xffffu), bf2f(v.x >> 16),
                     bf2f(v.y & 0xffffu), bf2f(v.y >> 16));
}
__device__ __forceinline__ void stbf4(unsigned short* p, float a, float b, float c, float d) {
  uint2 o;
  o.x = (unsigned int)f2bf(a) | ((unsigned int)f2bf(b) << 16);
  o.y = (unsigned int)f2bf(c) | ((unsigned int)f2bf(d) << 16);
  *(uint2*)p = o;
}

// ---------------- CSR build ----------------
__global__ __launch_bounds__(256) void zero_i_k(int* deg, int* cur, int n) {
  int i = blockIdx.x * 256 + threadIdx.x;
  if (i < n) { deg[i] = 0; cur[i] = 0; }
}

__global__ __launch_bounds__(256) void hist_k(const int* __restrict__ col, int* deg, int e) {
  int i = blockIdx.x * 256 + threadIdx.x;
  if (i < e) atomicAdd(&deg[col[i]], 1);
}

__global__ __launch_bounds__(256) void scanA_k(const int* __restrict__ deg,
                                               int* __restrict__ row_ptr,
                                               int* __restrict__ blockSums,
                                               float* __restrict__ dis, int n) {
  __shared__ int waveSums[4];
  const int tid = threadIdx.x, lane = tid & 63, w = tid >> 6;
  const int base = blockIdx.x * SCHUNK + tid * 4;
  int v0 = 0, v1 = 0, v2 = 0, v3 = 0;
  if (base + 0 < n) v0 = deg[base + 0];
  if (base + 1 < n) v1 = deg[base + 1];
  if (base + 2 < n) v2 = deg[base + 2];
  if (base + 3 < n) v3 = deg[base + 3];
  if (base + 0 < n) dis[base + 0] = rsqrtf((float)(v0 + 1));
  if (base + 1 < n) dis[base + 1] = rsqrtf((float)(v1 + 1));
  if (base + 2 < n) dis[base + 2] = rsqrtf((float)(v2 + 1));
  if (base + 3 < n) dis[base + 3] = rsqrtf((float)(v3 + 1));
  int tsum = v0 + v1 + v2 + v3;
  int inc = tsum;
#pragma unroll
  for (int off = 1; off < 64; off <<= 1) {
    int t = __shfl_up(inc, off);
    if (lane >= off) inc += t;
  }
  if (lane == 63) waveSums[w] = inc;
  __syncthreads();
  int woff = 0;
#pragma unroll
  for (int k = 0; k < 4; ++k) woff += (k < w) ? waveSums[k] : 0;
  int excl = woff + inc - tsum;
  if (base + 0 < n) row_ptr[base + 0] = excl;
  if (base + 1 < n) row_ptr[base + 1] = excl + v0;
  if (base + 2 < n) row_ptr[base + 2] = excl + v0 + v1;
  if (base + 3 < n) row_ptr[base + 3] = excl + v0 + v1 + v2;
  if (tid == 255) blockSums[blockIdx.x] = woff + inc;
}

__global__ __launch_bounds__(256) void scanB_k(int* blockSums, int nb) {
  __shared__ int waveSums[4];
  const int tid = threadIdx.x, lane = tid & 63, w = tid >> 6;
  int v = (tid < nb) ? blockSums[tid] : 0;
  int inc = v;
#pragma unroll
  for (int off = 1; off < 64; off <<= 1) {
    int t = __shfl_up(inc, off);
    if (lane >= off) inc += t;
  }
  if (lane == 63) waveSums[w] = inc;
  __syncthreads();
  int woff = 0;
#pragma unroll
  for (int k = 0; k < 4; ++k) woff += (k < w) ? waveSums[k] : 0;
  if (tid < nb) blockSums[tid] = woff + inc - v;
}

__global__ __launch_bounds__(256) void scanC_k(int* __restrict__ row_ptr,
                                               const int* __restrict__ blockSums,
                                               int n, int e) {
  const int base = blockIdx.x * SCHUNK + threadIdx.x * 4;
  const int add = blockSums[blockIdx.x];
#pragma unroll
  for (int k = 0; k < 4; ++k)
    if (base + k < n) row_ptr[base + k] += add;
  if (blockIdx.x == 0 && threadIdx.x == 0) row_ptr[n] = e;
}

__global__ __launch_bounds__(256) void fill_k(const int* __restrict__ row,
                                              const int* __restrict__ col,
                                              const int* __restrict__ row_ptr,
                                              int* cur, int* srcs, int e) {
  int i = blockIdx.x * 256 + threadIdx.x;
  if (i < e) {
    int c = col[i];
    int p = row_ptr[c] + atomicAdd(&cur[c], 1);
    srcs[p] = row[i];
  }
}

// ---------------- prep: pack 4 weights + cast x, one launch ----------------
// pack layout: [kb][ns][lane][j]; value = W[kb*32+(lane>>4)*8+j][ns*16+(lane&15)]
__device__ __forceinline__ void packW(const float* __restrict__ W,
                                      unsigned short* __restrict__ out,
                                      int idx, int C) {
  int j = idx & 7, lane = (idx >> 3) & 63, rest = idx >> 9;
  int NSUB = C >> 4;
  int ns = rest % NSUB, kb = rest / NSUB;
  int k = kb * 32 + (lane >> 4) * 8 + j;
  int c = ns * 16 + (lane & 15);
  out[idx] = f2bf(W[(size_t)k * C + c]);
}

__global__ __launch_bounds__(256) void prep_k(
    const float* __restrict__ W1, const float* __restrict__ W2,
    const float* __restrict__ W3, const float* __restrict__ Wf1,
    const float* __restrict__ x,
    unsigned short* __restrict__ W1p, unsigned short* __restrict__ W2p,
    unsigned short* __restrict__ W3p, unsigned short* __restrict__ Wf1p,
    unsigned short* __restrict__ xbf, int nx) {
  int idx = blockIdx.x * 256 + threadIdx.x;
  const int s0 = DIN * HDIM, s1 = s0 + HDIM * HDIM, s2 = s1 + HDIM * HDIM,
            s3 = s2 + HDIM * 128;
  if (idx < s0) packW(W1, W1p, idx, HDIM);
  else if (idx < s1) packW(W2, W2p, idx - s0, HDIM);
  else if (idx < s2) packW(W3, W3p, idx - s1, HDIM);
  else if (idx < s3) packW(Wf1, Wf1p, idx - s2, 128);
  else if (idx - s3 < nx) xbf[idx - s3] = f2bf(x[idx - s3]);
}

// ---------------- pure gather: out[i] = dis[i]*(sum dis[s]*x[s] + dis[i]*x[i]) ----
__global__ __launch_bounds__(256) void gather256_k(
    const unsigned short* __restrict__ x, const int* __restrict__ row_ptr,
    const int* __restrict__ srcs, const float* __restrict__ dis,
    unsigned short* __restrict__ out, int n) {
  int i = blockIdx.x * 4 + (threadIdx.x >> 6);
  int lane = threadIdx.x & 63;
  if (i >= n) return;
  int beg = row_ptr[i], end = row_ptr[i + 1];
  const int co = lane * 4;
  float di = dis[i];
  float4 sv = ldbf4(x + (size_t)i * 256 + co);
  float4 acc = make_float4(di * sv.x, di * sv.y, di * sv.z, di * sv.w);
  int j = beg;
  for (; j + 8 <= end; j += 8) {
    int r0 = srcs[j], r1 = srcs[j + 1], r2 = srcs[j + 2], r3 = srcs[j + 3];
    int r4 = srcs[j + 4], r5 = srcs[j + 5], r6 = srcs[j + 6], r7 = srcs[j + 7];
    float d0 = dis[r0], d1 = dis[r1], d2 = dis[r2], d3 = dis[r3];
    float d4 = dis[r4], d5 = dis[r5], d6 = dis[r6], d7 = dis[r7];
    float4 v0 = ldbf4(x + (size_t)r0 * 256 + co);
    float4 v1 = ldbf4(x + (size_t)r1 * 256 + co);
    float4 v2 = ldbf4(x + (size_t)r2 * 256 + co);
    float4 v3 = ldbf4(x + (size_t)r3 * 256 + co);
    float4 v4 = ldbf4(x + (size_t)r4 * 256 + co);
    float4 v5 = ldbf4(x + (size_t)r5 * 256 + co);
    float4 v6 = ldbf4(x + (size_t)r6 * 256 + co);
    float4 v7 = ldbf4(x + (size_t)r7 * 256 + co);
    acc.x += ((d0*v0.x + d1*v1.x) + (d2*v2.x + d3*v3.x)) + ((d4*v4.x + d5*v5.x) + (d6*v6.x + d7*v7.x));
    acc.y += ((d0*v0.y + d1*v1.y) + (d2*v2.y + d3*v3.y)) + ((d4*v4.y + d5*v5.y) + (d6*v6.y + d7*v7.y));
    acc.z += ((d0*v0.z + d1*v1.z) + (d2*v2.z + d3*v3.z)) + ((d4*v4.z + d5*v5.z) + (d6*v6.z + d7*v7.z));
    acc.w += ((d0*v0.w + d1*v1.w) + (d2*v2.w + d3*v3.w)) + ((d4*v4.w + d5*v5.w) + (d6*v6.w + d7*v7.w));
  }
  for (; j < end; ++j) {
    int r = srcs[j];
    float d = dis[r];
    float4 v = ldbf4(x + (size_t)r * 256 + co);
    acc.x += d * v.x; acc.y += d * v.y; acc.z += d * v.z; acc.w += d * v.w;
  }
  stbf4(out + (size_t)i * 256 + co, di * acc.x, di * acc.y, di * acc.z, di * acc.w);
}

__global__ __launch_bounds__(256) void gather128_k(
    const unsigned short* __restrict__ x, const int* __restrict__ row_ptr,
    const int* __restrict__ srcs, const float* __restrict__ dis,
    unsigned short* __restrict__ out, int n) {
  int i = blockIdx.x * 4 + (threadIdx.x >> 6);
  int lane = threadIdx.x & 63;
  if (i >= n) return;
  int beg = row_ptr[i], end = row_ptr[i + 1];
  const int co = lane * 2;
  float di = dis[i];
  unsigned int sv = *(const unsigned int*)(x + (size_t)i * 128 + co);
  float ax = di * bf2f(sv & 0xffffu), ay = di * bf2f(sv >> 16);
  int j = beg;
  for (; j + 8 <= end; j += 8) {
    int r0 = srcs[j], r1 = srcs[j + 1], r2 = srcs[j + 2], r3 = srcs[j + 3];
    int r4 = srcs[j + 4], r5 = srcs[j + 5], r6 = srcs[j + 6], r7 = srcs[j + 7];
    float d0 = dis[r0], d1 = dis[r1], d2 = dis[r2], d3 = dis[r3];
    float d4 = dis[r4], d5 = dis[r5], d6 = dis[r6], d7 = dis[r7];
    unsigned int u0 = *(const unsigned int*)(x + (size_t)r0 * 128 + co);
    unsigned int u1 = *(const unsigned int*)(x + (size_t)r1 * 128 + co);
    unsigned int u2 = *(const unsigned int*)(x + (size_t)r2 * 128 + co);
    unsigned int u3 = *(const unsigned int*)(x + (size_t)r3 * 128 + co);
    unsigned int u4 = *(const unsigned int*)(x + (size_t)r4 * 128 + co);
    unsigned int u5 = *(const unsigned int*)(x + (size_t)r5 * 128 + co);
    unsigned int u6 = *(const unsigned int*)(x + (size_t)r6 * 128 + co);
    unsigned int u7 = *(const unsigned int*)(x + (size_t)r7 * 128 + co);
    ax += ((d0*bf2f(u0&0xffffu) + d1*bf2f(u1&0xffffu)) + (d2*bf2f(u2&0xffffu) + d3*bf2f(u3&0xffffu)))
        + ((d4*bf2f(u4&0xffffu) + d5*bf2f(u5&0xffffu)) + (d6*bf2f(u6&0xffffu) + d7*bf2f(u7&0xffffu)));
    ay += ((d0*bf2f(u0>>16) + d1*bf2f(u1>>16)) + (d2*bf2f(u2>>16) + d3*bf2f(u3>>16)))
        + ((d4*bf2f(u4>>16) + d5*bf2f(u5>>16)) + (d6*bf2f(u6>>16) + d7*bf2f(u7>>16)));
  }
  for (; j < end; ++j) {
    int r = srcs[j];
    float d = dis[r];
    unsigned int u = *(const unsigned int*)(x + (size_t)r * 128 + co);
    ax += d * bf2f(u & 0xffffu);
    ay += d * bf2f(u >> 16);
  }
  unsigned int o = (unsigned int)f2bf(di * ax) | ((unsigned int)f2bf(di * ay) << 16);
  *(unsigned int*)(out + (size_t)i * 128 + co) = o;
}

// ---------------- GEMM + bias + LN + ReLU + residual, full 256-col rows --------
// 512 threads = 8 waves; wave = 32 rows x 64 cols; block = 64 rows x 256 cols.
// swapped operands: lane(gq,i) holds row m0+rg*32+rr*16+i, cols cg*64+j*16+gq*4+reg
// MODE 0: out=relu(ln); 1: +0.7*xprev; 2: *0.7+xprev
template<int MODE, int K>
__global__ __launch_bounds__(512) void gemmln_k(
    const unsigned short* __restrict__ A, const unsigned short* __restrict__ Wp,
    const float* __restrict__ bias, const float* __restrict__ gam,
    const float* __restrict__ bet, const unsigned short* __restrict__ xprev,
    unsigned short* __restrict__ out, int n) {
  constexpr int CN = 256, NSUB = 16, KC = K / 32;
  __shared__ float red_s[64][4], red_q[64][4];
  const int t = threadIdx.x;
  const int w = t >> 6, lane = t & 63;
  const int rg = w & 1, cg = w >> 1;
  const int gq = lane >> 4, i = lane & 15;
  const int m0 = blockIdx.x * 64;
  const int r0 = m0 + rg * 32 + i, r1 = r0 + 16;
  const int l0 = r0 < n ? r0 : n - 1, l1 = r1 < n ? r1 : n - 1;
  const unsigned short* a0 = A + (size_t)l0 * K + gq * 8;
  const unsigned short* a1 = A + (size_t)l1 * K + gq * 8;
  const short8* wp = (const short8*)Wp + (size_t)(cg * 4) * 64 + lane;

  f32x4 acc[2][4];
#pragma unroll
  for (int rr = 0; rr < 2; ++rr)
#pragma unroll
    for (int j = 0; j < 4; ++j) acc[rr][j] = (f32x4){0.f, 0.f, 0.f, 0.f};

  short8 af0 = *(const short8*)a0;
  short8 af1 = *(const short8*)a1;
  short8 wf[4];
#pragma unroll
  for (int j = 0; j < 4; ++j) wf[j] = wp[j * 64];

#pragma unroll
  for (int kc = 0; kc < KC; ++kc) {
    short8 naf0, naf1, nwf[4];
    if (kc + 1 < KC) {
      naf0 = *(const short8*)(a0 + (kc + 1) * 32);
      naf1 = *(const short8*)(a1 + (kc + 1) * 32);
#pragma unroll
      for (int j = 0; j < 4; ++j) nwf[j] = wp[(size_t)(kc + 1) * NSUB * 64 + j * 64];
    }
#pragma unroll
    for (int j = 0; j < 4; ++j) {
      acc[0][j] = __builtin_amdgcn_mfma_f32_16x16x32_bf16(wf[j], af0, acc[0][j], 0, 0, 0);
      acc[1][j] = __builtin_amdgcn_mfma_f32_16x16x32_bf16(wf[j], af1, acc[1][j], 0, 0, 0);
    }
    if (kc + 1 < KC) {
      af0 = naf0; af1 = naf1;
#pragma unroll
      for (int j = 0; j < 4; ++j) wf[j] = nwf[j];
    }
  }

  const int colb = cg * 64 + gq * 4;
  // add bias in place, compute per-lane partial sums
  float s0 = 0.f, q0 = 0.f, s1 = 0.f, q1 = 0.f;
#pragma unroll
  for (int j = 0; j < 4; ++j) {
    f32x4 b4 = *(const f32x4*)(bias + colb + j * 16);
#pragma unroll
    for (int r = 0; r < 4; ++r) {
      acc[0][j][r] += b4[r];
      acc[1][j][r] += b4[r];
      float v = acc[0][j][r]; s0 += v; q0 += v * v;
      float u = acc[1][j][r]; s1 += u; q1 += u * u;
    }
  }
  s0 += __shfl_xor(s0, 16); s0 += __shfl_xor(s0, 32);
  q0 += __shfl_xor(q0, 16); q0 += __shfl_xor(q0, 32);
  s1 += __shfl_xor(s1, 16); s1 += __shfl_xor(s1, 32);
  q1 += __shfl_xor(q1, 16); q1 += __shfl_xor(q1, 32);
  if (gq == 0) {
    red_s[rg * 32 + i][cg] = s0;      red_q[rg * 32 + i][cg] = q0;
    red_s[rg * 32 + 16 + i][cg] = s1; red_q[rg * 32 + 16 + i][cg] = q1;
  }
  __syncthreads();

#pragma unroll
  for (int rr = 0; rr < 2; ++rr) {
    int il = rg * 32 + rr * 16 + i;
    int r = m0 + il;
    if (r >= n) continue;
    float ss = (red_s[il][0] + red_s[il][1]) + (red_s[il][2] + red_s[il][3]);
    float qq = (red_q[il][0] + red_q[il][1]) + (red_q[il][2] + red_q[il][3]);
    float mu = ss * (1.f / CN);
    float inv = rsqrtf(qq * (1.f / CN) - mu * mu + EPSV);
    unsigned short* op = out + (size_t)r * CN + colb;
    const unsigned short* pp = (MODE != 0) ? (xprev + (size_t)r * CN + colb) : nullptr;
#pragma unroll
    for (int j = 0; j < 4; ++j) {
      f32x4 g4 = *(const f32x4*)(gam + colb + j * 16);
      f32x4 e4 = *(const f32x4*)(bet + colb + j * 16);
      float o0 = fmaxf((acc[rr][j][0] - mu) * inv * g4[0] + e4[0], 0.f);
      float o1 = fmaxf((acc[rr][j][1] - mu) * inv * g4[1] + e4[1], 0.f);
      float o2 = fmaxf((acc[rr][j][2] - mu) * inv * g4[2] + e4[2], 0.f);
      float o3 = fmaxf((acc[rr][j][3] - mu) * inv * g4[3] + e4[3], 0.f);
      if (MODE == 1) {
        float4 pv = ldbf4(pp + j * 16);
        o0 += 0.7f * pv.x; o1 += 0.7f * pv.y; o2 += 0.7f * pv.z; o3 += 0.7f * pv.w;
      } else if (MODE == 2) {
        float4 pv = ldbf4(pp + j * 16);
        o0 = o0 * 0.7f + pv.x; o1 = o1 * 0.7f + pv.y;
        o2 = o2 * 0.7f + pv.z; o3 = o3 * 0.7f + pv.w;
      }
      stbf4(op + j * 16, o0, o1, o2, o3);
    }
  }
}

// ---------------- fused MLP head: out[i] = relu(x3@Wf1+bf1) @ Wf2 + bf2 --------
// 256 threads = 4 waves; wave = 32 rows x 64 cols; block = 64 rows x 128 cols.
__global__ __launch_bounds__(256) void gemmdot_k(
    const unsigned short* __restrict__ A, const unsigned short* __restrict__ Wp,
    const float* __restrict__ b1, const float* __restrict__ w2,
    const float* __restrict__ b2, float* __restrict__ out, int n) {
  constexpr int K = 256, NSUB = 8, KC = 8;
  __shared__ float redh[64][2];
  const int t = threadIdx.x;
  const int w = t >> 6, lane = t & 63;
  const int rg = w & 1, cg = w >> 1;
  const int gq = lane >> 4, i = lane & 15;
  const int m0 = blockIdx.x * 64;
  const int r0 = m0 + rg * 32 + i, r1 = r0 + 16;
  const int l0 = r0 < n ? r0 : n - 1, l1 = r1 < n ? r1 : n - 1;
  const unsigned short* a0 = A + (size_t)l0 * K + gq * 8;
  const unsigned short* a1 = A + (size_t)l1 * K + gq * 8;
  const short8* wp = (const short8*)Wp + (size_t)(cg * 4) * 64 + lane;

  f32x4 acc[2][4];
#pragma unroll
  for (int rr = 0; rr < 2; ++rr)
#pragma unroll
    for (int j = 0; j < 4; ++j) acc[rr][j] = (f32x4){0.f, 0.f, 0.f, 0.f};

  short8 af0 = *(const short8*)a0;
  short8 af1 = *(const short8*)a1;
  short8 wf[4];
#pragma unroll
  for (int j = 0; j < 4; ++j) wf[j] = wp[j * 64];

#pragma unroll
  for (int kc = 0; kc < KC; ++kc) {
    short8 naf0, naf1, nwf[4];
    if (kc + 1 < KC) {
      naf0 = *(const short8*)(a0 + (kc + 1) * 32);
      naf1 = *(const short8*)(a1 + (kc + 1) * 32);
#pragma unroll
      for (int j = 0; j < 4; ++j) nwf[j] = wp[(size_t)(kc + 1) * NSUB * 64 + j * 64];
    }
#pragma unroll
    for (int j = 0; j < 4; ++j) {
      acc[0][j] = __builtin_amdgcn_mfma_f32_16x16x32_bf16(wf[j], af0, acc[0][j], 0, 0, 0);
      acc[1][j] = __builtin_amdgcn_mfma_f32_16x16x32_bf16(wf[j], af1, acc[1][j], 0, 0, 0);
    }
    if (kc + 1 < KC) {
      af0 = naf0; af1 = naf1;
#pragma unroll
      for (int j = 0; j < 4; ++j) wf[j] = nwf[j];
    }
  }

  const int colb = cg * 64 + gq * 4;
  float p0 = 0.f, p1 = 0.f;
#pragma unroll
  for (int j = 0; j < 4; ++j) {
    f32x4 bb = *(const f32x4*)(b1 + colb + j * 16);
    f32x4 ww = *(const f32x4*)(w2 + colb + j * 16);
#pragma unroll
    for (int r = 0; r < 4; ++r) {
      p0 += fmaxf(acc[0][j][r] + bb[r], 0.f) * ww[r];
      p1 += fmaxf(acc[1][j][r] + bb[r], 0.f) * ww[r];
    }
  }
  p0 += __shfl_xor(p0, 16); p0 += __shfl_xor(p0, 32);
  p1 += __shfl_xor(p1, 16); p1 += __shfl_xor(p1, 32);
  if (gq == 0) {
    redh[rg * 32 + i][cg] = p0;
    redh[rg * 32 + 16 + i][cg] = p1;
  }
  __syncthreads();
  if (t < 64) {
    int r = m0 + t;
    if (r < n) out[r] = redh[t][0] + redh[t][1] + b2[0];
  }
}

extern "C" void kernel_launch(void* const* d_in, const int* in_sizes, int n_in,
                              void* d_out, int out_size, void* d_ws, size_t ws_size,
                              hipStream_t stream) {
  const float* x   = (const float*)d_in[0];
  const int*   ei  = (const int*)d_in[1];
  const float* W1  = (const float*)d_in[2];
  const float* b1  = (const float*)d_in[3];
  const float* g1  = (const float*)d_in[4];
  const float* be1 = (const float*)d_in[5];
  const float* W2  = (const float*)d_in[6];
  const float* b2  = (const float*)d_in[7];
  const float* g2  = (const float*)d_in[8];
  const float* be2 = (const float*)d_in[9];
  const float* W3  = (const float*)d_in[10];
  const float* b3  = (const float*)d_in[11];
  const float* g3  = (const float*)d_in[12];
  const float* be3 = (const float*)d_in[13];
  const float* Wf1 = (const float*)d_in[14];
  const float* bf1 = (const float*)d_in[15];
  const float* Wf2 = (const float*)d_in[16];
  const float* bf2 = (const float*)d_in[17];
  float* out = (float*)d_out;

  const int n = in_sizes[0] / DIN;   // 50000
  const int e = in_sizes[1] / 2;     // 800000
  const int* row = ei;               // sources
  const int* col = ei + e;           // targets

  char* ws = (char*)d_ws;
  size_t off = 0;
  auto alloc = [&](size_t bytes) -> void* {
    void* p = ws + off;
    off = (off + bytes + 255) & ~(size_t)255;
    return p;
  };
  float*          dis     = (float*)alloc((size_t)n * 4);
  int*            deg_i   = (int*)alloc((size_t)n * 4);
  int*            cur     = (int*)alloc((size_t)n * 4);
  int*            row_ptr = (int*)alloc((size_t)(n + 1) * 4);
  int*            bsums   = (int*)alloc((size_t)256 * 4);
  int*            srcs    = (int*)alloc((size_t)e * 4);
  unsigned short* W1p     = (unsigned short*)alloc((size_t)DIN * HDIM * 2);
  unsigned short* W2p     = (unsigned short*)alloc((size_t)HDIM * HDIM * 2);
  unsigned short* W3p     = (unsigned short*)alloc((size_t)HDIM * HDIM * 2);
  unsigned short* Wf1p    = (unsigned short*)alloc((size_t)HDIM * 128 * 2);
  unsigned short* xbf     = (unsigned short*)alloc((size_t)n * DIN * 2);
  unsigned short* agg     = (unsigned short*)alloc((size_t)n * HDIM * 2);
  unsigned short* x1      = (unsigned short*)alloc((size_t)n * HDIM * 2);
  unsigned short* x2      = (unsigned short*)alloc((size_t)n * HDIM * 2);
  unsigned short* a1      = agg;   // layer-1 aggregate [n,128], reuses agg
  unsigned short* x3      = x1;    // x1 dead after gemmln<1> consumed it

  const int nb  = (n + 255) / 256;
  const int eb  = (e + 255) / 256;
  const int lnb = (n + 3) / 4;
  const int gb  = (n + 63) / 64;
  const int sb_ = (n + SCHUNK - 1) / SCHUNK;
  const int prep_tot = DIN * HDIM + HDIM * HDIM + HDIM * HDIM + HDIM * 128 + n * DIN;

  // CSR build + normalization
  zero_i_k<<<nb, 256, 0, stream>>>(deg_i, cur, n);
  hist_k<<<eb, 256, 0, stream>>>(col, deg_i, e);
  scanA_k<<<sb_, 256, 0, stream>>>(deg_i, row_ptr, bsums, dis, n);
  scanB_k<<<1, 256, 0, stream>>>(bsums, sb_);
  scanC_k<<<sb_, 256, 0, stream>>>(row_ptr, bsums, n, e);
  fill_k<<<eb, 256, 0, stream>>>(row, col, row_ptr, cur, srcs, e);

  // weight packs + input cast (single launch)
  prep_k<<<(prep_tot + 255) / 256, 256, 0, stream>>>(W1, W2, W3, Wf1, x,
                                                     W1p, W2p, W3p, Wf1p, xbf, n * DIN);

  // layer 1: aggregate 128-dim, then GEMM+LN
  gather128_k<<<lnb, 256, 0, stream>>>(xbf, row_ptr, srcs, dis, a1, n);
  gemmln_k<0, DIN><<<gb, 512, 0, stream>>>(a1, W1p, b1, g1, be1, nullptr, x1, n);

  // layer 2
  gather256_k<<<lnb, 256, 0, stream>>>(x1, row_ptr, srcs, dis, agg, n);
  gemmln_k<1, HDIM><<<gb, 512, 0, stream>>>(agg, W2p, b2, g2, be2, x1, x2, n);

  // layer 3
  gather256_k<<<lnb, 256, 0, stream>>>(x2, row_ptr, srcs, dis, agg, n);
  gemmln_k<2, HDIM><<<gb, 512, 0, stream>>>(agg, W3p, b3, g3, be3, x2, x3, n);

  // fused MLP head (h never materialized)
  gemmdot_k<<<gb, 256, 0, stream>>>(x3, Wf1p, bf1, Wf2, bf2, out, n);
}